// Round 10
// baseline (369.904 us; speedup 1.0000x reference)
//
#include <hip/hip_runtime.h>
#include <stdint.h>

typedef unsigned short u16;
typedef __attribute__((ext_vector_type(8))) short bf16x8;
typedef __attribute__((ext_vector_type(4))) float f32x4;

__device__ __forceinline__ float b2f(u16 u) {
    union { float f; uint32_t u; } v; v.u = ((uint32_t)u) << 16; return v.f;
}
__device__ __forceinline__ u16 f2b(float f) {
    union { float f; uint32_t u; } v; v.f = f;
    uint32_t r = v.u + 0x7FFFu + ((v.u >> 16) & 1u);
    return (u16)(r >> 16);
}
// HW packed f32->bf16 (RNE): 2 values in 1 instruction (no builtin on gfx950)
__device__ __forceinline__ uint32_t cvt_pk_bf16(float lo, float hi) {
    uint32_t r;
    asm("v_cvt_pk_bf16_f32 %0, %1, %2" : "=v"(r) : "v"(lo), "v"(hi));
    return r;
}

// DPP cross-lane move (row_ror:N = 0x120+N; quad_perm = 0x00..0xFF). Full-rate VALU.
template <int CTRL>
__device__ __forceinline__ float dppf(float x) {
    union { float f; int i; } u; u.f = x;
    u.i = __builtin_amdgcn_update_dpp(0, u.i, CTRL, 0xF, 0xF, false);
    return u.f;
}
// all-lanes max/sum over each 16-lane DPP row via rotate-reduce
__device__ __forceinline__ float rowmax16(float v) {
    v = fmaxf(v, dppf<0x121>(v));   // ror 1
    v = fmaxf(v, dppf<0x122>(v));   // ror 2
    v = fmaxf(v, dppf<0x124>(v));   // ror 4
    v = fmaxf(v, dppf<0x128>(v));   // ror 8
    return v;
}
__device__ __forceinline__ float rowsum16(float v) {
    v += dppf<0x121>(v);
    v += dppf<0x122>(v);
    v += dppf<0x124>(v);
    v += dppf<0x128>(v);
    return v;
}

// async global->LDS, 16B/lane. LDS dest must be wave-uniform; HW adds lane*16.
__device__ __forceinline__ void stage16(const void* g, void* l) {
    __builtin_amdgcn_global_load_lds(
        (const __attribute__((address_space(1))) uint32_t*)(uintptr_t)g,
        (__attribute__((address_space(3))) uint32_t*)(uint32_t)(uintptr_t)l,
        16, 0, 0);
}

// ---- fused preprocessing: 5 weight transposes + rmsnorm1 + rope cos/sin table ----
// blocks 0..12543: transpose tiles; 12544..16639: rmsnorm rows; 16640..16895: table.
__global__ __launch_bounds__(256) void prep_kernel(const float* __restrict__ Wqkv,
                                                   const float* __restrict__ Wattn,
                                                   const float* __restrict__ Wfc1,
                                                   const float* __restrict__ Wfc2,
                                                   const float* __restrict__ Wmlp,
                                                   u16* WtQ, u16* WtA, u16* WtF1,
                                                   u16* WtF2, u16* WtM,
                                                   const float* __restrict__ xin,
                                                   const float* __restrict__ scale,
                                                   u16* __restrict__ xout,
                                                   float2* __restrict__ ctab) {
    const int tx = threadIdx.x, ty = threadIdx.y; // 32 x 8
    int id = blockIdx.x;
    if (id >= 16640) {
        // ---- rope table: ctab[tpos*32 + j] = {cos, sin}(tpos * 10000^(-j/32)) ----
        const int e = (id - 16640) * 256 + ty * 32 + tx;   // 0..65535
        const int tpos = e >> 5, j = e & 31;
        const float theta = expf(-(float)j * (9.210340371976184f / 32.0f));
        const float ang = (float)tpos * theta;
        ctab[e] = make_float2(cosf(ang), sinf(ang));
        return;
    }
    if (id >= 12544) {
        // ---- rmsnorm path ----
        const int row = id - 12544, tid = ty * 32 + tx;
        const float4 v = ((const float4*)(xin + (size_t)row * 1024))[tid];
        float ss = v.x * v.x + v.y * v.y + v.z * v.z + v.w * v.w;
        #pragma unroll
        for (int d = 32; d; d >>= 1) ss += __shfl_xor(ss, d);
        __shared__ float wsum[4];
        if ((tid & 63) == 0) wsum[tid >> 6] = ss;
        __syncthreads();
        const float r = rsqrtf((wsum[0] + wsum[1] + wsum[2] + wsum[3]) * (1.f / 1024.f) + 1e-5f);
        const float4 sc = ((const float4*)scale)[tid];
        uint2 o;
        o.x = cvt_pk_bf16(v.x * sc.x * r, v.y * sc.y * r);
        o.y = cvt_pk_bf16(v.z * sc.z * r, v.w * sc.w * r);
        ((uint2*)(xout + (size_t)row * 1024))[tid] = o;
        return;
    }
    // ---- transpose path ----
    __shared__ u16 tile[32][33];
    const float* src; u16* dst; int R, C;
    if (id < 3072)      {             src = Wqkv;  dst = WtQ;  R = 1024; C = 3072; }
    else if (id < 4096) { id -= 3072; src = Wattn; dst = WtA;  R = 1024; C = 1024; }
    else if (id < 6912) { id -= 4096; src = Wfc1;  dst = WtF1; R = 1024; C = 2816; }
    else if (id < 9728) { id -= 6912; src = Wfc2;  dst = WtF2; R = 1024; C = 2816; }
    else                { id -= 9728; src = Wmlp;  dst = WtM;  R = 2816; C = 1024; }
    const int nbx = C >> 5;
    const int bx = id % nbx, by = id / nbx;
    const int cx = bx * 32, ry = by * 32;
    #pragma unroll
    for (int i = 0; i < 32; i += 8)
        tile[ty + i][tx] = f2b(src[(size_t)(ry + ty + i) * C + cx + tx]);
    __syncthreads();
    #pragma unroll
    for (int i = 0; i < 32; i += 8)
        dst[(size_t)(cx + ty + i) * R + ry + tx] = tile[tx][ty + i];
}

// ---- rmsnorm (row = 1024): fp32 in, fp32 scale, bf16 out ----
__global__ __launch_bounds__(256) void rmsnorm_f32(const float* __restrict__ xin,
                                                   const float* __restrict__ scale,
                                                   u16* __restrict__ out) {
    const int row = blockIdx.x, tid = threadIdx.x;
    const float4 v = ((const float4*)(xin + (size_t)row * 1024))[tid];
    float ss = v.x * v.x + v.y * v.y + v.z * v.z + v.w * v.w;
    #pragma unroll
    for (int d = 32; d; d >>= 1) ss += __shfl_xor(ss, d);
    __shared__ float wsum[4];
    if ((tid & 63) == 0) wsum[tid >> 6] = ss;
    __syncthreads();
    const float r = rsqrtf((wsum[0] + wsum[1] + wsum[2] + wsum[3]) * (1.f / 1024.f) + 1e-5f);
    const float4 sc = ((const float4*)scale)[tid];
    uint2 o;
    o.x = cvt_pk_bf16(v.x * sc.x * r, v.y * sc.y * r);
    o.y = cvt_pk_bf16(v.z * sc.z * r, v.w * sc.w * r);
    ((uint2*)(out + (size_t)row * 1024))[tid] = o;
}

// ---- qkv GEMM with FUSED RoPE epilogue: A (M x 1024) bf16, Bt (3072 x 1024) bf16.
// 128x128 tile, 2x BK=32 halves per barrier pair. Blocks x<16 cover q,k columns:
// the rope pair (2j, 2j+1) sits in ADJACENT LANES (col = ...+t), so one DPP
// quad_perm[1,0,3,2] exchange + fma applies rope on f32 acc before bf16 store
// (removes the rope kernel AND its bf16 double-rounding). ctab L2-resident.
__global__ __launch_bounds__(256) void gemm_qkv(const u16* __restrict__ A,
                                                const u16* __restrict__ Bt,
                                                u16* __restrict__ Cout,
                                                const float2* __restrict__ ctab,
                                                int N, int K) {
    __shared__ __attribute__((aligned(16))) u16 As[2][128 * 32];
    __shared__ __attribute__((aligned(16))) u16 Bs[2][128 * 32];
    const int tid = threadIdx.x;
    const int w = tid >> 6, lane = tid & 63;
    const int quad = lane >> 4, t = lane & 15;
    const int m0 = blockIdx.y * 128, n0 = blockIdx.x * 128;
    const int wm = (w >> 1) * 64, wn = (w & 1) * 64;

    const int srow = w * 16 + (lane >> 2);
    const int scol = (lane & 3) * 8;
    const u16* pA0 = A + (size_t)(m0 + srow) * K + scol;
    const u16* pA1 = pA0 + (size_t)64 * K;
    const u16* pB0 = Bt + (size_t)(n0 + srow) * K + scol;
    const u16* pB1 = pB0 + (size_t)64 * K;

    f32x4 acc[4][4];
    #pragma unroll
    for (int i = 0; i < 4; ++i)
        #pragma unroll
        for (int j = 0; j < 4; ++j) acc[i][j] = (f32x4){0.f, 0.f, 0.f, 0.f};

    for (int kb = 0; kb < K; kb += 64) {
        __syncthreads();
        stage16(pA0 + kb,      (char*)As[0] + w * 1024);
        stage16(pA1 + kb,      (char*)As[0] + 4096 + w * 1024);
        stage16(pB0 + kb,      (char*)Bs[0] + w * 1024);
        stage16(pB1 + kb,      (char*)Bs[0] + 4096 + w * 1024);
        stage16(pA0 + kb + 32, (char*)As[1] + w * 1024);
        stage16(pA1 + kb + 32, (char*)As[1] + 4096 + w * 1024);
        stage16(pB0 + kb + 32, (char*)Bs[1] + w * 1024);
        stage16(pB1 + kb + 32, (char*)Bs[1] + 4096 + w * 1024);
        __syncthreads();
        #pragma unroll
        for (int hf = 0; hf < 2; ++hf) {
            bf16x8 af[4], bfr[4];
            #pragma unroll
            for (int mi = 0; mi < 4; ++mi)
                af[mi] = *(const bf16x8*)((char*)As[hf] + (wm + mi * 16 + t) * 64 + quad * 16);
            #pragma unroll
            for (int ni = 0; ni < 4; ++ni)
                bfr[ni] = *(const bf16x8*)((char*)Bs[hf] + (wn + ni * 16 + t) * 64 + quad * 16);
            #pragma unroll
            for (int mi = 0; mi < 4; ++mi)
                #pragma unroll
                for (int ni = 0; ni < 4; ++ni)
                    acc[mi][ni] = __builtin_amdgcn_mfma_f32_16x16x32_bf16(af[mi], bfr[ni],
                                                                         acc[mi][ni], 0, 0, 0);
        }
    }
    if (blockIdx.x < 16) {
        // ---- q,k columns: rope on f32 acc ----
        const float sgn = (t & 1) ? 1.f : -1.f;   // odd lane: +s ; even lane: -s
        #pragma unroll
        for (int mi = 0; mi < 4; ++mi) {
            const int row0 = m0 + wm + mi * 16 + quad * 4;
            #pragma unroll
            for (int ni = 0; ni < 4; ++ni) {
                const int col = n0 + wn + ni * 16 + t;
                const int j = (ni * 16 + t) >> 1;          // rope freq index 0..31
                #pragma unroll
                for (int r = 0; r < 4; ++r) {
                    const int row = row0 + r;
                    const float2 cs = ctab[(size_t)(row & 2047) * 32 + j];
                    const float own = acc[mi][ni][r];
                    const float par = dppf<0xB1>(own);     // quad_perm [1,0,3,2]
                    Cout[(size_t)row * N + col] = f2b(own * cs.x + par * (sgn * cs.y));
                }
            }
        }
    } else {
        // ---- v columns: plain store ----
        #pragma unroll
        for (int mi = 0; mi < 4; ++mi) {
            const int row0 = m0 + wm + mi * 16 + quad * 4;
            #pragma unroll
            for (int ni = 0; ni < 4; ++ni) {
                const int col = n0 + wn + ni * 16 + t;
                #pragma unroll
                for (int r = 0; r < 4; ++r)
                    Cout[(size_t)(row0 + r) * N + col] = f2b(acc[mi][ni][r]);
            }
        }
    }
}

// ---- GEMM variant: 128x64 tile for N=1024 shapes (512 blocks -> 2 blocks/CU),
// same 2x BK=32 unroll ----
template <int EPI>
__global__ __launch_bounds__(256) void gemm_bt64(const u16* __restrict__ A,
                                                 const u16* __restrict__ Bt,
                                                 void* __restrict__ Cout,
                                                 const float* __restrict__ Res,
                                                 int N, int K) {
    __shared__ __attribute__((aligned(16))) u16 As[2][128 * 32];  // 16 KB
    __shared__ __attribute__((aligned(16))) u16 Bs[2][64 * 32];   // 8 KB
    const int tid = threadIdx.x;
    const int w = tid >> 6, lane = tid & 63;
    const int quad = lane >> 4, t = lane & 15;
    const int m0 = blockIdx.y * 128, n0 = blockIdx.x * 64;
    const int wm = (w >> 1) * 64, wn = (w & 1) * 32;

    const int srow = w * 16 + (lane >> 2);
    const int scol = (lane & 3) * 8;
    const u16* pA0 = A + (size_t)(m0 + srow) * K + scol;
    const u16* pA1 = pA0 + (size_t)64 * K;
    const u16* pB0 = Bt + (size_t)(n0 + srow) * K + scol;

    f32x4 acc[4][2];
    #pragma unroll
    for (int i = 0; i < 4; ++i)
        #pragma unroll
        for (int j = 0; j < 2; ++j) acc[i][j] = (f32x4){0.f, 0.f, 0.f, 0.f};

    for (int kb = 0; kb < K; kb += 64) {
        __syncthreads();
        stage16(pA0 + kb,      (char*)As[0] + w * 1024);
        stage16(pA1 + kb,      (char*)As[0] + 4096 + w * 1024);
        stage16(pB0 + kb,      (char*)Bs[0] + w * 1024);
        stage16(pA0 + kb + 32, (char*)As[1] + w * 1024);
        stage16(pA1 + kb + 32, (char*)As[1] + 4096 + w * 1024);
        stage16(pB0 + kb + 32, (char*)Bs[1] + w * 1024);
        __syncthreads();
        #pragma unroll
        for (int hf = 0; hf < 2; ++hf) {
            bf16x8 af[4], bfr[2];
            #pragma unroll
            for (int mi = 0; mi < 4; ++mi)
                af[mi] = *(const bf16x8*)((char*)As[hf] + (wm + mi * 16 + t) * 64 + quad * 16);
            #pragma unroll
            for (int ni = 0; ni < 2; ++ni)
                bfr[ni] = *(const bf16x8*)((char*)Bs[hf] + (wn + ni * 16 + t) * 64 + quad * 16);
            #pragma unroll
            for (int mi = 0; mi < 4; ++mi)
                #pragma unroll
                for (int ni = 0; ni < 2; ++ni)
                    acc[mi][ni] = __builtin_amdgcn_mfma_f32_16x16x32_bf16(af[mi], bfr[ni],
                                                                         acc[mi][ni], 0, 0, 0);
        }
    }
    #pragma unroll
    for (int mi = 0; mi < 4; ++mi) {
        const int row0 = m0 + wm + mi * 16 + quad * 4;
        #pragma unroll
        for (int ni = 0; ni < 2; ++ni) {
            const int col = n0 + wn + ni * 16 + t;
            #pragma unroll
            for (int r = 0; r < 4; ++r) {
                const size_t idx = (size_t)(row0 + r) * N + col;
                const float v = acc[mi][ni][r];
                if (EPI == 0) ((u16*)Cout)[idx]   = f2b(v);
                else          ((float*)Cout)[idx] = v + Res[idx];
            }
        }
    }
}

// ---- FUSED fc1+fc2 GEMM: A (M x K), B1t/B2t (N x K); C = silu(A@W1) * (A@W2).
// A staged ONCE for both B operands; silu-mul in-register; one dispatch.
__global__ __launch_bounds__(256) void gemm_fc(const u16* __restrict__ A,
                                               const u16* __restrict__ B1t,
                                               const u16* __restrict__ B2t,
                                               u16* __restrict__ Cout,
                                               int N, int K) {
    __shared__ __attribute__((aligned(16))) u16 As[2][128 * 32];   // 16 KB
    __shared__ __attribute__((aligned(16))) u16 B1s[2][64 * 32];   // 8 KB
    __shared__ __attribute__((aligned(16))) u16 B2s[2][64 * 32];   // 8 KB
    const int tid = threadIdx.x;
    const int w = tid >> 6, lane = tid & 63;
    const int quad = lane >> 4, t = lane & 15;
    const int m0 = blockIdx.y * 128, n0 = blockIdx.x * 64;
    const int wm = (w >> 1) * 64, wn = (w & 1) * 32;

    const int srow = w * 16 + (lane >> 2);
    const int scol = (lane & 3) * 8;
    const u16* pA0 = A + (size_t)(m0 + srow) * K + scol;
    const u16* pA1 = pA0 + (size_t)64 * K;
    const u16* pB1 = B1t + (size_t)(n0 + srow) * K + scol;
    const u16* pB2 = B2t + (size_t)(n0 + srow) * K + scol;

    f32x4 acc1[4][2], acc2[4][2];
    #pragma unroll
    for (int i = 0; i < 4; ++i)
        #pragma unroll
        for (int j = 0; j < 2; ++j) {
            acc1[i][j] = (f32x4){0.f, 0.f, 0.f, 0.f};
            acc2[i][j] = (f32x4){0.f, 0.f, 0.f, 0.f};
        }

    for (int kb = 0; kb < K; kb += 64) {
        __syncthreads();
        stage16(pA0 + kb,      (char*)As[0] + w * 1024);
        stage16(pA1 + kb,      (char*)As[0] + 4096 + w * 1024);
        stage16(pB1 + kb,      (char*)B1s[0] + w * 1024);
        stage16(pB2 + kb,      (char*)B2s[0] + w * 1024);
        stage16(pA0 + kb + 32, (char*)As[1] + w * 1024);
        stage16(pA1 + kb + 32, (char*)As[1] + 4096 + w * 1024);
        stage16(pB1 + kb + 32, (char*)B1s[1] + w * 1024);
        stage16(pB2 + kb + 32, (char*)B2s[1] + w * 1024);
        __syncthreads();
        #pragma unroll
        for (int hf = 0; hf < 2; ++hf) {
            bf16x8 af[4], b1r[2], b2r[2];
            #pragma unroll
            for (int mi = 0; mi < 4; ++mi)
                af[mi] = *(const bf16x8*)((char*)As[hf] + (wm + mi * 16 + t) * 64 + quad * 16);
            #pragma unroll
            for (int ni = 0; ni < 2; ++ni) {
                b1r[ni] = *(const bf16x8*)((char*)B1s[hf] + (wn + ni * 16 + t) * 64 + quad * 16);
                b2r[ni] = *(const bf16x8*)((char*)B2s[hf] + (wn + ni * 16 + t) * 64 + quad * 16);
            }
            #pragma unroll
            for (int mi = 0; mi < 4; ++mi)
                #pragma unroll
                for (int ni = 0; ni < 2; ++ni) {
                    acc1[mi][ni] = __builtin_amdgcn_mfma_f32_16x16x32_bf16(af[mi], b1r[ni],
                                                                          acc1[mi][ni], 0, 0, 0);
                    acc2[mi][ni] = __builtin_amdgcn_mfma_f32_16x16x32_bf16(af[mi], b2r[ni],
                                                                          acc2[mi][ni], 0, 0, 0);
                }
        }
    }
    #pragma unroll
    for (int mi = 0; mi < 4; ++mi) {
        const int row0 = m0 + wm + mi * 16 + quad * 4;
        #pragma unroll
        for (int ni = 0; ni < 2; ++ni) {
            const int col = n0 + wn + ni * 16 + t;
            float mv[4];
            #pragma unroll
            for (int r = 0; r < 4; ++r) {
                const float a = acc1[mi][ni][r];
                mv[r] = (a / (1.f + __expf(-a))) * acc2[mi][ni][r];
            }
            #pragma unroll
            for (int r = 0; r < 4; r += 2) {
                const uint32_t pk2 = cvt_pk_bf16(mv[r], mv[r + 1]);
                Cout[(size_t)(row0 + r) * N + col]     = (u16)pk2;
                Cout[(size_t)(row0 + r + 1) * N + col] = (u16)(pk2 >> 16);
            }
        }
    }
}

// ---- flash attention: qkv (4096 x 3072 bf16, roped), y (4096 x 1024 bf16) ----
// Pair-balanced (block does q-tiles (31-pairk) then (pairk) = 33 uniform K-tiles)
// + XCD-GROUPED mapping (FETCH 97 -> 12 MB measured). DPP softmax; diagonal-only
// mask; folded Q-scale; Vts XOR-swizzled. R8 form (cvt_pk asm in the softmax chain
// regressed -2% - m240 lesson: scalar f2b schedules better inside the serial chain).
__global__ __launch_bounds__(256) void attn_kernel(const u16* __restrict__ qkv,
                                                   const int* __restrict__ ymask,
                                                   u16* __restrict__ y) {
    const int gid = blockIdx.x;              // 0..511
    const int xcd = gid & 7;
    const int j2 = gid >> 3;                 // 0..63
    const int slot = j2 >> 4;                // 0..3
    const int pairk = j2 & 15;               // 0..15
    const int group = slot * 8 + xcd;        // 0..31
    const int h = group & 15, b = group >> 4;
    const int tid = threadIdx.x;
    const int w = tid >> 6, lane = tid & 63;
    const int quad = lane >> 4, t = lane & 15;

    __shared__ __attribute__((aligned(16))) u16 Ks[64 * 72];    // [key][d], 144B rows
    __shared__ __attribute__((aligned(16))) u16 Vts[64 * 72];   // [d][key], swizzled
    __shared__ __attribute__((aligned(16))) u16 Ps[4][16 * 72]; // per-wave P [m][key]
    __shared__ int ymL[64];
    if (pairk == 0 && tid < 64) ymL[tid] = ymask[b * 64 + tid];

    // staging assignment: thread -> (key = tid>>3 and +32, dg = tid&7)
    const int skey = tid >> 3, sdg = tid & 7;
    const u16* pK = qkv + (size_t)(b * 2048 + skey) * 3072 + h * 64 + sdg * 8 + 1024;
    const int sblk0 = (skey >> 3) ^ sdg;          // Vts block for keys 0..31 set
    const int sblk1 = (4 + (skey >> 3)) ^ sdg;    // keys 32..63 set

    for (int seg = 0; seg < 2; ++seg) {
        const int qt = seg ? pairk : 31 - pairk;  // long segment first
        const int q0 = qt * 64;

        bf16x8 aQ[2];
        {
            const u16* qp = qkv + (size_t)(b * 2048 + q0 + w * 16 + t) * 3072 + h * 64 + quad * 8;
            aQ[0] = *(const bf16x8*)qp;
            aQ[1] = *(const bf16x8*)(qp + 32);
            #pragma unroll
            for (int i = 0; i < 8; ++i) {   // fold 1/sqrt(64): *2^-3 exact in bf16
                aQ[0][i] = (short)f2b(b2f((u16)aQ[0][i]) * 0.125f);
                aQ[1][i] = (short)f2b(b2f((u16)aQ[1][i]) * 0.125f);
            }
        }

        f32x4 accO[4] = {(f32x4){0,0,0,0},(f32x4){0,0,0,0},(f32x4){0,0,0,0},(f32x4){0,0,0,0}};
        float mOld[4] = {-INFINITY, -INFINITY, -INFINITY, -INFINITY};
        float lSum[4] = {0.f, 0.f, 0.f, 0.f};

        for (int kb = 0; kb <= qt; ++kb) {
            // global loads issued before the barrier (latency overlaps drain)
            const u16* pk = pK + (size_t)kb * 196608;        // kb*64*3072
            const uint4 kv0 = *(const uint4*)pk;
            const uint4 vv0 = *(const uint4*)(pk + 1024);
            const uint4 kv1 = *(const uint4*)(pk + 98304);   // +32*3072
            const uint4 vv1 = *(const uint4*)(pk + 99328);
            __syncthreads();                 // prior iteration's LDS reads done
            *(uint4*)((char*)Ks + skey * 144 + sdg * 16) = kv0;
            *(uint4*)((char*)Ks + (skey + 32) * 144 + sdg * 16) = kv1;
            {
                const u16* vp0 = (const u16*)&vv0;
                const u16* vp1 = (const u16*)&vv1;
                #pragma unroll
                for (int jj = 0; jj < 8; ++jj) {
                    const int row = sdg * 8 + jj;
                    Vts[row * 72 + sblk0 * 8 + (skey & 7)] = vp0[jj];
                    Vts[row * 72 + sblk1 * 8 + (skey & 7)] = vp1[jj];
                }
            }
            __syncthreads();

            float s[4][4];
            __builtin_amdgcn_s_setprio(1);
            #pragma unroll
            for (int ni = 0; ni < 4; ++ni) {
                bf16x8 bK0 = *(const bf16x8*)((char*)Ks + (ni * 16 + t) * 144 + quad * 16);
                bf16x8 bK1 = *(const bf16x8*)((char*)Ks + (ni * 16 + t) * 144 + 64 + quad * 16);
                f32x4 sa = (f32x4){0.f, 0.f, 0.f, 0.f};
                sa = __builtin_amdgcn_mfma_f32_16x16x32_bf16(aQ[0], bK0, sa, 0, 0, 0);
                sa = __builtin_amdgcn_mfma_f32_16x16x32_bf16(aQ[1], bK1, sa, 0, 0, 0);
                #pragma unroll
                for (int r = 0; r < 4; ++r) s[ni][r] = sa[r];
            }
            __builtin_amdgcn_s_setprio(0);

            // mask only on the diagonal tile; ym text-mask only in the qt==0 tile.
            if (kb == qt) {
                const int irow = q0 + w * 16 + quad * 4;
                #pragma unroll
                for (int ni = 0; ni < 4; ++ni)
                    #pragma unroll
                    for (int r = 0; r < 4; ++r) {
                        const int i = irow + r, j = kb * 64 + ni * 16 + t;
                        const bool ok = (j <= i) || (qt == 0 && ymL[i & 63] && ymL[j & 63]);
                        if (!ok) s[ni][r] = -INFINITY;
                    }
            }

            float alpha[4];
            bool upd = false;
            #pragma unroll
            for (int r = 0; r < 4; ++r) {
                float mt = fmaxf(fmaxf(s[0][r], s[1][r]), fmaxf(s[2][r], s[3][r]));
                mt = rowmax16(mt);                       // DPP, VALU-rate
                const float mNew = fmaxf(mOld[r], mt);
                upd = upd || (mNew > mOld[r]);
                alpha[r] = __expf(mOld[r] - mNew);
                #pragma unroll
                for (int ni = 0; ni < 4; ++ni) s[ni][r] = __expf(s[ni][r] - mNew);
                mOld[r] = mNew;
            }

            // P (C-layout) -> per-wave LDS, issued early; ds_write latency hides
            // under the DPP sum-reduces below. Same-wave, no barrier needed.
            u16* Pw = Ps[w];
            #pragma unroll
            for (int ni = 0; ni < 4; ++ni)
                #pragma unroll
                for (int r = 0; r < 4; ++r)
                    Pw[(quad * 4 + r) * 72 + ni * 16 + t] = f2b(s[ni][r]);

            #pragma unroll
            for (int r = 0; r < 4; ++r) {
                float rs = (s[0][r] + s[1][r]) + (s[2][r] + s[3][r]);
                rs = rowsum16(rs);                       // DPP, VALU-rate
                lSum[r] = lSum[r] * alpha[r] + rs;
            }
            if (__any(upd)) {               // skip O-rescale when no row's max moved
                #pragma unroll
                for (int dt = 0; dt < 4; ++dt)
                    #pragma unroll
                    for (int r = 0; r < 4; ++r) accO[dt][r] *= alpha[r];
            }

            bf16x8 aP0 = *(const bf16x8*)((char*)Pw + t * 144 + quad * 16);
            bf16x8 aP1 = *(const bf16x8*)((char*)Pw + t * 144 + 64 + quad * 16);
            __builtin_amdgcn_s_setprio(1);
            #pragma unroll
            for (int dt = 0; dt < 4; ++dt) {
                const int row = dt * 16 + t, rb = row >> 3;
                bf16x8 bV0 = *(const bf16x8*)((char*)Vts + row * 144 + ((quad ^ rb) << 4));
                bf16x8 bV1 = *(const bf16x8*)((char*)Vts + row * 144 + (((4 + quad) ^ rb) << 4));
                accO[dt] = __builtin_amdgcn_mfma_f32_16x16x32_bf16(aP0, bV0, accO[dt], 0, 0, 0);
                accO[dt] = __builtin_amdgcn_mfma_f32_16x16x32_bf16(aP1, bV1, accO[dt], 0, 0, 0);
            }
            __builtin_amdgcn_s_setprio(0);
        }
        const int orow = q0 + w * 16 + quad * 4;
        #pragma unroll
        for (int dt = 0; dt < 4; ++dt)
            #pragma unroll
            for (int r = 0; r < 4; ++r) {
                const size_t idx = (size_t)(b * 2048 + orow + r) * 1024 + h * 64 + dt * 16 + t;
                y[idx] = f2b(accO[dt][r] / lSum[r]);
            }
    }
}

extern "C" void kernel_launch(void* const* d_in, const int* in_sizes, int n_in,
                              void* d_out, int out_size, void* d_ws, size_t ws_size,
                              hipStream_t stream) {
    const float* x     = (const float*)d_in[0];
    const int*   ym    = (const int*)d_in[1];
    const float* Wqkv  = (const float*)d_in[2];
    const float* Wattn = (const float*)d_in[3];
    const float* s1    = (const float*)d_in[4];
    const float* s2    = (const float*)d_in[5];
    const float* Wfc1  = (const float*)d_in[6];
    const float* Wfc2  = (const float*)d_in[7];
    const float* Wmlp  = (const float*)d_in[8];

    char* ws = (char*)d_ws;
    u16*    h    = (u16*)(ws + 0);          // 8 MB bf16; reused as attention output
    u16*    qkv  = (u16*)(ws + 8388608);    // 24 MB bf16; later reused as fc1/m
    u16*    fc1  = qkv;
    float*  xr   = (float*)(ws + 33554432); // 16 MB fp32 residual
    u16*    WtA  = (u16*)(ws + 50331648);   // 2 MB
    u16*    WtF1 = (u16*)(ws + 52428800);   // 5.5 MB
    u16*    WtF2 = (u16*)(ws + 58195968);   // 5.5 MB
    u16*    WtM  = (u16*)(ws + 63963136);   // 5.5 MB (ends 69730304)
    float2* ctab = (float2*)(ws + 69730304);// 512 KB rope cos/sin table
    u16*    WtQ  = (u16*)(ws + 73400320);   // 6 MB
    const dim3 tb(32, 8);

    prep_kernel<<<16896, tb, 0, stream>>>(Wqkv, Wattn, Wfc1, Wfc2, Wmlp,
                                          WtQ, WtA, WtF1, WtF2, WtM, x, s1, h, ctab);
    gemm_qkv<<<dim3(24, 32), 256, 0, stream>>>(h, WtQ, qkv, ctab, 3072, 1024);
    attn_kernel<<<512, 256, 0, stream>>>(qkv, ym, h);   // h dead -> y
    gemm_bt64<1><<<dim3(16, 32), 256, 0, stream>>>(h, WtA, xr, x, 1024, 1024);
    rmsnorm_f32<<<4096, 256, 0, stream>>>(xr, s2, h);
    gemm_fc<<<dim3(44, 32), 256, 0, stream>>>(h, WtF1, WtF2, fc1, 2816, 1024);
    gemm_bt64<1><<<dim3(16, 32), 256, 0, stream>>>(fc1, WtM, (float*)d_out, xr, 1024, 2816);
}

// Round 11
// 359.085 us; speedup vs baseline: 1.0301x; 1.0301x over previous
//
#include <hip/hip_runtime.h>
#include <stdint.h>

typedef unsigned short u16;
typedef __attribute__((ext_vector_type(8))) short bf16x8;
typedef __attribute__((ext_vector_type(4))) float f32x4;

__device__ __forceinline__ float b2f(u16 u) {
    union { float f; uint32_t u; } v; v.u = ((uint32_t)u) << 16; return v.f;
}
__device__ __forceinline__ u16 f2b(float f) {
    union { float f; uint32_t u; } v; v.f = f;
    uint32_t r = v.u + 0x7FFFu + ((v.u >> 16) & 1u);
    return (u16)(r >> 16);
}
// HW packed f32->bf16 (RNE): 2 values in 1 instruction (no builtin on gfx950)
__device__ __forceinline__ uint32_t cvt_pk_bf16(float lo, float hi) {
    uint32_t r;
    asm("v_cvt_pk_bf16_f32 %0, %1, %2" : "=v"(r) : "v"(lo), "v"(hi));
    return r;
}

// DPP cross-lane move within 16-lane rows (row_ror:N = 0x120+N). Full-rate VALU.
template <int CTRL>
__device__ __forceinline__ float dppf(float x) {
    union { float f; int i; } u; u.f = x;
    u.i = __builtin_amdgcn_update_dpp(0, u.i, CTRL, 0xF, 0xF, false);
    return u.f;
}
// all-lanes max/sum over each 16-lane DPP row via rotate-reduce
__device__ __forceinline__ float rowmax16(float v) {
    v = fmaxf(v, dppf<0x121>(v));   // ror 1
    v = fmaxf(v, dppf<0x122>(v));   // ror 2
    v = fmaxf(v, dppf<0x124>(v));   // ror 4
    v = fmaxf(v, dppf<0x128>(v));   // ror 8
    return v;
}
__device__ __forceinline__ float rowsum16(float v) {
    v += dppf<0x121>(v);
    v += dppf<0x122>(v);
    v += dppf<0x124>(v);
    v += dppf<0x128>(v);
    return v;
}

// async global->LDS, 16B/lane. LDS dest must be wave-uniform; HW adds lane*16.
__device__ __forceinline__ void stage16(const void* g, void* l) {
    __builtin_amdgcn_global_load_lds(
        (const __attribute__((address_space(1))) uint32_t*)(uintptr_t)g,
        (__attribute__((address_space(3))) uint32_t*)(uint32_t)(uintptr_t)l,
        16, 0, 0);
}

// XCD-grouped block remap (nwg must be divisible by 8): blocks with lid%8==c land
// on XCD c (round-robin dispatch, HW-confirmed by attn FETCH 97->12MB); give each
// XCD a CONTIGUOUS m-range so its A-slice stays L2-resident across the n-sweep.
__device__ __forceinline__ void xcd_remap(int& bx, int& by) {
    const int gx = gridDim.x;
    const int lid = blockIdx.x + blockIdx.y * gx;
    const int nwg = gx * gridDim.y;
    const int nlid = (lid & 7) * (nwg >> 3) + (lid >> 3);
    bx = nlid % gx;
    by = nlid / gx;
}

// ---- fused preprocessing: 5 weight transposes + rmsnorm1, ONE launch ----
// blocks 0..12543: transpose tiles; blocks 12544..16639: rmsnorm rows.
__global__ __launch_bounds__(256) void prep_kernel(const float* __restrict__ Wqkv,
                                                   const float* __restrict__ Wattn,
                                                   const float* __restrict__ Wfc1,
                                                   const float* __restrict__ Wfc2,
                                                   const float* __restrict__ Wmlp,
                                                   u16* WtQ, u16* WtA, u16* WtF1,
                                                   u16* WtF2, u16* WtM,
                                                   const float* __restrict__ xin,
                                                   const float* __restrict__ scale,
                                                   u16* __restrict__ xout) {
    const int tx = threadIdx.x, ty = threadIdx.y; // 32 x 8
    int id = blockIdx.x;
    if (id >= 12544) {
        // ---- rmsnorm path ----
        const int row = id - 12544, tid = ty * 32 + tx;
        const float4 v = ((const float4*)(xin + (size_t)row * 1024))[tid];
        float ss = v.x * v.x + v.y * v.y + v.z * v.z + v.w * v.w;
        #pragma unroll
        for (int d = 32; d; d >>= 1) ss += __shfl_xor(ss, d);
        __shared__ float wsum[4];
        if ((tid & 63) == 0) wsum[tid >> 6] = ss;
        __syncthreads();
        const float r = rsqrtf((wsum[0] + wsum[1] + wsum[2] + wsum[3]) * (1.f / 1024.f) + 1e-5f);
        const float4 sc = ((const float4*)scale)[tid];
        uint2 o;
        o.x = cvt_pk_bf16(v.x * sc.x * r, v.y * sc.y * r);
        o.y = cvt_pk_bf16(v.z * sc.z * r, v.w * sc.w * r);
        ((uint2*)(xout + (size_t)row * 1024))[tid] = o;
        return;
    }
    // ---- transpose path ----
    __shared__ u16 tile[32][33];
    const float* src; u16* dst; int R, C;
    if (id < 3072)      {             src = Wqkv;  dst = WtQ;  R = 1024; C = 3072; }
    else if (id < 4096) { id -= 3072; src = Wattn; dst = WtA;  R = 1024; C = 1024; }
    else if (id < 6912) { id -= 4096; src = Wfc1;  dst = WtF1; R = 1024; C = 2816; }
    else if (id < 9728) { id -= 6912; src = Wfc2;  dst = WtF2; R = 1024; C = 2816; }
    else                { id -= 9728; src = Wmlp;  dst = WtM;  R = 2816; C = 1024; }
    const int nbx = C >> 5;
    const int bx = id % nbx, by = id / nbx;
    const int cx = bx * 32, ry = by * 32;
    #pragma unroll
    for (int i = 0; i < 32; i += 8)
        tile[ty + i][tx] = f2b(src[(size_t)(ry + ty + i) * C + cx + tx]);
    __syncthreads();
    #pragma unroll
    for (int i = 0; i < 32; i += 8)
        dst[(size_t)(cx + ty + i) * R + ry + tx] = tile[tx][ty + i];
}

// ---- rmsnorm (row = 1024): fp32 in, fp32 scale, bf16 out ----
__global__ __launch_bounds__(256) void rmsnorm_f32(const float* __restrict__ xin,
                                                   const float* __restrict__ scale,
                                                   u16* __restrict__ out) {
    const int row = blockIdx.x, tid = threadIdx.x;
    const float4 v = ((const float4*)(xin + (size_t)row * 1024))[tid];
    float ss = v.x * v.x + v.y * v.y + v.z * v.z + v.w * v.w;
    #pragma unroll
    for (int d = 32; d; d >>= 1) ss += __shfl_xor(ss, d);
    __shared__ float wsum[4];
    if ((tid & 63) == 0) wsum[tid >> 6] = ss;
    __syncthreads();
    const float r = rsqrtf((wsum[0] + wsum[1] + wsum[2] + wsum[3]) * (1.f / 1024.f) + 1e-5f);
    const float4 sc = ((const float4*)scale)[tid];
    uint2 o;
    o.x = cvt_pk_bf16(v.x * sc.x * r, v.y * sc.y * r);
    o.y = cvt_pk_bf16(v.z * sc.z * r, v.w * sc.w * r);
    ((uint2*)(out + (size_t)row * 1024))[tid] = o;
}

// ---- RoPE in place on q,k thirds of qkv (4096 x 3072 bf16) ----
// One thread per (row, i): trig computed ONCE, applied to 16 q-heads + 16 k-heads
// via coalesced u32 accesses (lanes 0..31 span i -> 128B contiguous per head).
__global__ __launch_bounds__(256) void rope_kernel(u16* __restrict__ qkv) {
    const int gid = blockIdx.x * 256 + threadIdx.x;  // 131072 = 4096 rows * 32 i
    const int i = gid & 31;
    const int row = gid >> 5;
    const int tpos = row & 2047;
    const float theta = expf(-(float)i * (9.210340371976184f / 32.0f));
    const float ang = (float)tpos * theta;
    const float c = cosf(ang), s = sinf(ang);
    uint32_t* p = (uint32_t*)qkv + (size_t)row * 1536 + i;
    #pragma unroll
    for (int h = 0; h < 16; ++h) {
        const uint32_t uq = p[h * 32];
        {
            const float xe = b2f((u16)(uq & 0xffff)), xo = b2f((u16)(uq >> 16));
            p[h * 32] = cvt_pk_bf16(xe * c - xo * s, xe * s + xo * c);
        }
        const uint32_t uk = p[512 + h * 32];
        {
            const float xe = b2f((u16)(uk & 0xffff)), xo = b2f((u16)(uk >> 16));
            p[512 + h * 32] = cvt_pk_bf16(xe * c - xo * s, xe * s + xo * c);
        }
    }
}

// ---- GEMM: A (M x K) bf16, Bt (N x K) bf16, 128x128 tile, 2x BK=32 halves per
// barrier pair (8 stage16 in flight, 32 MFMA per drain -> half the barrier stalls).
// XCD-grouped block mapping. EPI 0: Cbf16; EPI 1: Cf32 = acc + Res_f32
template <int EPI>
__global__ __launch_bounds__(256) void gemm_bt(const u16* __restrict__ A,
                                               const u16* __restrict__ Bt,
                                               void* __restrict__ Cout,
                                               const void* __restrict__ Res,
                                               int N, int K) {
    __shared__ __attribute__((aligned(16))) u16 As[2][128 * 32];
    __shared__ __attribute__((aligned(16))) u16 Bs[2][128 * 32];
    const int tid = threadIdx.x;
    const int w = tid >> 6, lane = tid & 63;
    const int quad = lane >> 4, t = lane & 15;
    int bx, by;
    xcd_remap(bx, by);
    const int m0 = by * 128, n0 = bx * 128;
    const int wm = (w >> 1) * 64, wn = (w & 1) * 64;

    const int srow = w * 16 + (lane >> 2);
    const int scol = (lane & 3) * 8;
    const u16* pA0 = A + (size_t)(m0 + srow) * K + scol;
    const u16* pA1 = pA0 + (size_t)64 * K;
    const u16* pB0 = Bt + (size_t)(n0 + srow) * K + scol;
    const u16* pB1 = pB0 + (size_t)64 * K;

    f32x4 acc[4][4];
    #pragma unroll
    for (int i = 0; i < 4; ++i)
        #pragma unroll
        for (int j = 0; j < 4; ++j) acc[i][j] = (f32x4){0.f, 0.f, 0.f, 0.f};

    for (int kb = 0; kb < K; kb += 64) {
        __syncthreads();                 // prior iteration's LDS reads complete
        stage16(pA0 + kb,      (char*)As[0] + w * 1024);
        stage16(pA1 + kb,      (char*)As[0] + 4096 + w * 1024);
        stage16(pB0 + kb,      (char*)Bs[0] + w * 1024);
        stage16(pB1 + kb,      (char*)Bs[0] + 4096 + w * 1024);
        stage16(pA0 + kb + 32, (char*)As[1] + w * 1024);
        stage16(pA1 + kb + 32, (char*)As[1] + 4096 + w * 1024);
        stage16(pB0 + kb + 32, (char*)Bs[1] + w * 1024);
        stage16(pB1 + kb + 32, (char*)Bs[1] + 4096 + w * 1024);
        __syncthreads();                 // vmcnt(0) drain: staging visible
        #pragma unroll
        for (int hf = 0; hf < 2; ++hf) {
            bf16x8 af[4], bfr[4];
            #pragma unroll
            for (int mi = 0; mi < 4; ++mi)
                af[mi] = *(const bf16x8*)((char*)As[hf] + (wm + mi * 16 + t) * 64 + quad * 16);
            #pragma unroll
            for (int ni = 0; ni < 4; ++ni)
                bfr[ni] = *(const bf16x8*)((char*)Bs[hf] + (wn + ni * 16 + t) * 64 + quad * 16);
            #pragma unroll
            for (int mi = 0; mi < 4; ++mi)
                #pragma unroll
                for (int ni = 0; ni < 4; ++ni)
                    acc[mi][ni] = __builtin_amdgcn_mfma_f32_16x16x32_bf16(af[mi], bfr[ni],
                                                                         acc[mi][ni], 0, 0, 0);
        }
    }
    #pragma unroll
    for (int mi = 0; mi < 4; ++mi) {
        const int row0 = m0 + wm + mi * 16 + quad * 4;
        #pragma unroll
        for (int ni = 0; ni < 4; ++ni) {
            const int col = n0 + wn + ni * 16 + t;
            #pragma unroll
            for (int r = 0; r < 4; r += 2) {
                const size_t idx0 = (size_t)(row0 + r) * N + col;
                const size_t idx1 = (size_t)(row0 + r + 1) * N + col;
                if (EPI == 0) {
                    const uint32_t pk2 = cvt_pk_bf16(acc[mi][ni][r], acc[mi][ni][r + 1]);
                    ((u16*)Cout)[idx0] = (u16)pk2;
                    ((u16*)Cout)[idx1] = (u16)(pk2 >> 16);
                } else {
                    ((float*)Cout)[idx0] = acc[mi][ni][r]     + ((const float*)Res)[idx0];
                    ((float*)Cout)[idx1] = acc[mi][ni][r + 1] + ((const float*)Res)[idx1];
                }
            }
        }
    }
}

// ---- GEMM variant: 128x64 tile for N=1024 shapes (512 blocks -> 2 blocks/CU),
// same 2x BK=32 unroll, XCD-grouped mapping ----
template <int EPI>
__global__ __launch_bounds__(256) void gemm_bt64(const u16* __restrict__ A,
                                                 const u16* __restrict__ Bt,
                                                 void* __restrict__ Cout,
                                                 const float* __restrict__ Res,
                                                 int N, int K) {
    __shared__ __attribute__((aligned(16))) u16 As[2][128 * 32];  // 16 KB
    __shared__ __attribute__((aligned(16))) u16 Bs[2][64 * 32];   // 8 KB
    const int tid = threadIdx.x;
    const int w = tid >> 6, lane = tid & 63;
    const int quad = lane >> 4, t = lane & 15;
    int bx, by;
    xcd_remap(bx, by);
    const int m0 = by * 128, n0 = bx * 64;
    const int wm = (w >> 1) * 64, wn = (w & 1) * 32;

    const int srow = w * 16 + (lane >> 2);
    const int scol = (lane & 3) * 8;
    const u16* pA0 = A + (size_t)(m0 + srow) * K + scol;
    const u16* pA1 = pA0 + (size_t)64 * K;
    const u16* pB0 = Bt + (size_t)(n0 + srow) * K + scol;

    f32x4 acc[4][2];
    #pragma unroll
    for (int i = 0; i < 4; ++i)
        #pragma unroll
        for (int j = 0; j < 2; ++j) acc[i][j] = (f32x4){0.f, 0.f, 0.f, 0.f};

    for (int kb = 0; kb < K; kb += 64) {
        __syncthreads();
        stage16(pA0 + kb,      (char*)As[0] + w * 1024);
        stage16(pA1 + kb,      (char*)As[0] + 4096 + w * 1024);
        stage16(pB0 + kb,      (char*)Bs[0] + w * 1024);
        stage16(pA0 + kb + 32, (char*)As[1] + w * 1024);
        stage16(pA1 + kb + 32, (char*)As[1] + 4096 + w * 1024);
        stage16(pB0 + kb + 32, (char*)Bs[1] + w * 1024);
        __syncthreads();
        #pragma unroll
        for (int hf = 0; hf < 2; ++hf) {
            bf16x8 af[4], bfr[2];
            #pragma unroll
            for (int mi = 0; mi < 4; ++mi)
                af[mi] = *(const bf16x8*)((char*)As[hf] + (wm + mi * 16 + t) * 64 + quad * 16);
            #pragma unroll
            for (int ni = 0; ni < 2; ++ni)
                bfr[ni] = *(const bf16x8*)((char*)Bs[hf] + (wn + ni * 16 + t) * 64 + quad * 16);
            #pragma unroll
            for (int mi = 0; mi < 4; ++mi)
                #pragma unroll
                for (int ni = 0; ni < 2; ++ni)
                    acc[mi][ni] = __builtin_amdgcn_mfma_f32_16x16x32_bf16(af[mi], bfr[ni],
                                                                         acc[mi][ni], 0, 0, 0);
        }
    }
    #pragma unroll
    for (int mi = 0; mi < 4; ++mi) {
        const int row0 = m0 + wm + mi * 16 + quad * 4;
        #pragma unroll
        for (int ni = 0; ni < 2; ++ni) {
            const int col = n0 + wn + ni * 16 + t;
            #pragma unroll
            for (int r = 0; r < 4; ++r) {
                const size_t idx = (size_t)(row0 + r) * N + col;
                const float v = acc[mi][ni][r];
                if (EPI == 0) ((u16*)Cout)[idx]   = f2b(v);
                else          ((float*)Cout)[idx] = v + Res[idx];
            }
        }
    }
}

// ---- FUSED fc1+fc2 GEMM: A (M x K), B1t/B2t (N x K); C = silu(A@W1) * (A@W2).
// A staged ONCE for both B operands; silu-mul in-register; XCD-grouped mapping.
__global__ __launch_bounds__(256) void gemm_fc(const u16* __restrict__ A,
                                               const u16* __restrict__ B1t,
                                               const u16* __restrict__ B2t,
                                               u16* __restrict__ Cout,
                                               int N, int K) {
    __shared__ __attribute__((aligned(16))) u16 As[2][128 * 32];   // 16 KB
    __shared__ __attribute__((aligned(16))) u16 B1s[2][64 * 32];   // 8 KB
    __shared__ __attribute__((aligned(16))) u16 B2s[2][64 * 32];   // 8 KB
    const int tid = threadIdx.x;
    const int w = tid >> 6, lane = tid & 63;
    const int quad = lane >> 4, t = lane & 15;
    int bx, by;
    xcd_remap(bx, by);
    const int m0 = by * 128, n0 = bx * 64;
    const int wm = (w >> 1) * 64, wn = (w & 1) * 32;

    const int srow = w * 16 + (lane >> 2);
    const int scol = (lane & 3) * 8;
    const u16* pA0 = A + (size_t)(m0 + srow) * K + scol;
    const u16* pA1 = pA0 + (size_t)64 * K;
    const u16* pB1 = B1t + (size_t)(n0 + srow) * K + scol;
    const u16* pB2 = B2t + (size_t)(n0 + srow) * K + scol;

    f32x4 acc1[4][2], acc2[4][2];
    #pragma unroll
    for (int i = 0; i < 4; ++i)
        #pragma unroll
        for (int j = 0; j < 2; ++j) {
            acc1[i][j] = (f32x4){0.f, 0.f, 0.f, 0.f};
            acc2[i][j] = (f32x4){0.f, 0.f, 0.f, 0.f};
        }

    for (int kb = 0; kb < K; kb += 64) {
        __syncthreads();
        stage16(pA0 + kb,      (char*)As[0] + w * 1024);
        stage16(pA1 + kb,      (char*)As[0] + 4096 + w * 1024);
        stage16(pB1 + kb,      (char*)B1s[0] + w * 1024);
        stage16(pB2 + kb,      (char*)B2s[0] + w * 1024);
        stage16(pA0 + kb + 32, (char*)As[1] + w * 1024);
        stage16(pA1 + kb + 32, (char*)As[1] + 4096 + w * 1024);
        stage16(pB1 + kb + 32, (char*)B1s[1] + w * 1024);
        stage16(pB2 + kb + 32, (char*)B2s[1] + w * 1024);
        __syncthreads();
        #pragma unroll
        for (int hf = 0; hf < 2; ++hf) {
            bf16x8 af[4], b1r[2], b2r[2];
            #pragma unroll
            for (int mi = 0; mi < 4; ++mi)
                af[mi] = *(const bf16x8*)((char*)As[hf] + (wm + mi * 16 + t) * 64 + quad * 16);
            #pragma unroll
            for (int ni = 0; ni < 2; ++ni) {
                b1r[ni] = *(const bf16x8*)((char*)B1s[hf] + (wn + ni * 16 + t) * 64 + quad * 16);
                b2r[ni] = *(const bf16x8*)((char*)B2s[hf] + (wn + ni * 16 + t) * 64 + quad * 16);
            }
            #pragma unroll
            for (int mi = 0; mi < 4; ++mi)
                #pragma unroll
                for (int ni = 0; ni < 2; ++ni) {
                    acc1[mi][ni] = __builtin_amdgcn_mfma_f32_16x16x32_bf16(af[mi], b1r[ni],
                                                                          acc1[mi][ni], 0, 0, 0);
                    acc2[mi][ni] = __builtin_amdgcn_mfma_f32_16x16x32_bf16(af[mi], b2r[ni],
                                                                          acc2[mi][ni], 0, 0, 0);
                }
        }
    }
    #pragma unroll
    for (int mi = 0; mi < 4; ++mi) {
        const int row0 = m0 + wm + mi * 16 + quad * 4;
        #pragma unroll
        for (int ni = 0; ni < 2; ++ni) {
            const int col = n0 + wn + ni * 16 + t;
            float mv[4];
            #pragma unroll
            for (int r = 0; r < 4; ++r) {
                const float a = acc1[mi][ni][r];
                mv[r] = (a / (1.f + __expf(-a))) * acc2[mi][ni][r];
            }
            #pragma unroll
            for (int r = 0; r < 4; r += 2) {
                const uint32_t pk2 = cvt_pk_bf16(mv[r], mv[r + 1]);
                Cout[(size_t)(row0 + r) * N + col]     = (u16)pk2;
                Cout[(size_t)(row0 + r + 1) * N + col] = (u16)(pk2 >> 16);
            }
        }
    }
}

// ---- flash attention: qkv (4096 x 3072 bf16, roped), y (4096 x 1024 bf16) ----
// Pair-balanced (block does q-tiles (31-pairk) then (pairk) = 33 uniform K-tiles)
// + XCD-GROUPED mapping (FETCH 97 -> 12 MB measured). DPP softmax; diagonal-only
// mask; folded Q-scale; Vts XOR-swizzled. R8 form (cvt_pk asm in the softmax chain
// regressed -2% - m240 lesson: scalar f2b schedules better inside the serial chain).
__global__ __launch_bounds__(256) void attn_kernel(const u16* __restrict__ qkv,
                                                   const int* __restrict__ ymask,
                                                   u16* __restrict__ y) {
    const int gid = blockIdx.x;              // 0..511
    const int xcd = gid & 7;
    const int j2 = gid >> 3;                 // 0..63
    const int slot = j2 >> 4;                // 0..3
    const int pairk = j2 & 15;               // 0..15
    const int group = slot * 8 + xcd;        // 0..31
    const int h = group & 15, b = group >> 4;
    const int tid = threadIdx.x;
    const int w = tid >> 6, lane = tid & 63;
    const int quad = lane >> 4, t = lane & 15;

    __shared__ __attribute__((aligned(16))) u16 Ks[64 * 72];    // [key][d], 144B rows
    __shared__ __attribute__((aligned(16))) u16 Vts[64 * 72];   // [d][key], swizzled
    __shared__ __attribute__((aligned(16))) u16 Ps[4][16 * 72]; // per-wave P [m][key]
    __shared__ int ymL[64];
    if (pairk == 0 && tid < 64) ymL[tid] = ymask[b * 64 + tid];

    // staging assignment: thread -> (key = tid>>3 and +32, dg = tid&7)
    const int skey = tid >> 3, sdg = tid & 7;
    const u16* pK = qkv + (size_t)(b * 2048 + skey) * 3072 + h * 64 + sdg * 8 + 1024;
    const int sblk0 = (skey >> 3) ^ sdg;          // Vts block for keys 0..31 set
    const int sblk1 = (4 + (skey >> 3)) ^ sdg;    // keys 32..63 set

    for (int seg = 0; seg < 2; ++seg) {
        const int qt = seg ? pairk : 31 - pairk;  // long segment first
        const int q0 = qt * 64;

        bf16x8 aQ[2];
        {
            const u16* qp = qkv + (size_t)(b * 2048 + q0 + w * 16 + t) * 3072 + h * 64 + quad * 8;
            aQ[0] = *(const bf16x8*)qp;
            aQ[1] = *(const bf16x8*)(qp + 32);
            #pragma unroll
            for (int i = 0; i < 8; ++i) {   // fold 1/sqrt(64): *2^-3 exact in bf16
                aQ[0][i] = (short)f2b(b2f((u16)aQ[0][i]) * 0.125f);
                aQ[1][i] = (short)f2b(b2f((u16)aQ[1][i]) * 0.125f);
            }
        }

        f32x4 accO[4] = {(f32x4){0,0,0,0},(f32x4){0,0,0,0},(f32x4){0,0,0,0},(f32x4){0,0,0,0}};
        float mOld[4] = {-INFINITY, -INFINITY, -INFINITY, -INFINITY};
        float lSum[4] = {0.f, 0.f, 0.f, 0.f};

        for (int kb = 0; kb <= qt; ++kb) {
            // global loads issued before the barrier (latency overlaps drain)
            const u16* pk = pK + (size_t)kb * 196608;        // kb*64*3072
            const uint4 kv0 = *(const uint4*)pk;
            const uint4 vv0 = *(const uint4*)(pk + 1024);
            const uint4 kv1 = *(const uint4*)(pk + 98304);   // +32*3072
            const uint4 vv1 = *(const uint4*)(pk + 99328);
            __syncthreads();                 // prior iteration's LDS reads done
            *(uint4*)((char*)Ks + skey * 144 + sdg * 16) = kv0;
            *(uint4*)((char*)Ks + (skey + 32) * 144 + sdg * 16) = kv1;
            {
                const u16* vp0 = (const u16*)&vv0;
                const u16* vp1 = (const u16*)&vv1;
                #pragma unroll
                for (int jj = 0; jj < 8; ++jj) {
                    const int row = sdg * 8 + jj;
                    Vts[row * 72 + sblk0 * 8 + (skey & 7)] = vp0[jj];
                    Vts[row * 72 + sblk1 * 8 + (skey & 7)] = vp1[jj];
                }
            }
            __syncthreads();

            float s[4][4];
            __builtin_amdgcn_s_setprio(1);
            #pragma unroll
            for (int ni = 0; ni < 4; ++ni) {
                bf16x8 bK0 = *(const bf16x8*)((char*)Ks + (ni * 16 + t) * 144 + quad * 16);
                bf16x8 bK1 = *(const bf16x8*)((char*)Ks + (ni * 16 + t) * 144 + 64 + quad * 16);
                f32x4 sa = (f32x4){0.f, 0.f, 0.f, 0.f};
                sa = __builtin_amdgcn_mfma_f32_16x16x32_bf16(aQ[0], bK0, sa, 0, 0, 0);
                sa = __builtin_amdgcn_mfma_f32_16x16x32_bf16(aQ[1], bK1, sa, 0, 0, 0);
                #pragma unroll
                for (int r = 0; r < 4; ++r) s[ni][r] = sa[r];
            }
            __builtin_amdgcn_s_setprio(0);

            // mask only on the diagonal tile; ym text-mask only in the qt==0 tile.
            if (kb == qt) {
                const int irow = q0 + w * 16 + quad * 4;
                #pragma unroll
                for (int ni = 0; ni < 4; ++ni)
                    #pragma unroll
                    for (int r = 0; r < 4; ++r) {
                        const int i = irow + r, j = kb * 64 + ni * 16 + t;
                        const bool ok = (j <= i) || (qt == 0 && ymL[i & 63] && ymL[j & 63]);
                        if (!ok) s[ni][r] = -INFINITY;
                    }
            }

            float alpha[4];
            bool upd = false;
            #pragma unroll
            for (int r = 0; r < 4; ++r) {
                float mt = fmaxf(fmaxf(s[0][r], s[1][r]), fmaxf(s[2][r], s[3][r]));
                mt = rowmax16(mt);                       // DPP, VALU-rate
                const float mNew = fmaxf(mOld[r], mt);
                upd = upd || (mNew > mOld[r]);
                alpha[r] = __expf(mOld[r] - mNew);
                #pragma unroll
                for (int ni = 0; ni < 4; ++ni) s[ni][r] = __expf(s[ni][r] - mNew);
                mOld[r] = mNew;
            }

            // P (C-layout) -> per-wave LDS, issued early; ds_write latency hides
            // under the DPP sum-reduces below. Same-wave, no barrier needed.
            u16* Pw = Ps[w];
            #pragma unroll
            for (int ni = 0; ni < 4; ++ni)
                #pragma unroll
                for (int r = 0; r < 4; ++r)
                    Pw[(quad * 4 + r) * 72 + ni * 16 + t] = f2b(s[ni][r]);

            #pragma unroll
            for (int r = 0; r < 4; ++r) {
                float rs = (s[0][r] + s[1][r]) + (s[2][r] + s[3][r]);
                rs = rowsum16(rs);                       // DPP, VALU-rate
                lSum[r] = lSum[r] * alpha[r] + rs;
            }
            if (__any(upd)) {               // skip O-rescale when no row's max moved
                #pragma unroll
                for (int dt = 0; dt < 4; ++dt)
                    #pragma unroll
                    for (int r = 0; r < 4; ++r) accO[dt][r] *= alpha[r];
            }

            bf16x8 aP0 = *(const bf16x8*)((char*)Pw + t * 144 + quad * 16);
            bf16x8 aP1 = *(const bf16x8*)((char*)Pw + t * 144 + 64 + quad * 16);
            __builtin_amdgcn_s_setprio(1);
            #pragma unroll
            for (int dt = 0; dt < 4; ++dt) {
                const int row = dt * 16 + t, rb = row >> 3;
                bf16x8 bV0 = *(const bf16x8*)((char*)Vts + row * 144 + ((quad ^ rb) << 4));
                bf16x8 bV1 = *(const bf16x8*)((char*)Vts + row * 144 + (((4 + quad) ^ rb) << 4));
                accO[dt] = __builtin_amdgcn_mfma_f32_16x16x32_bf16(aP0, bV0, accO[dt], 0, 0, 0);
                accO[dt] = __builtin_amdgcn_mfma_f32_16x16x32_bf16(aP1, bV1, accO[dt], 0, 0, 0);
            }
            __builtin_amdgcn_s_setprio(0);
        }
        const int orow = q0 + w * 16 + quad * 4;
        #pragma unroll
        for (int dt = 0; dt < 4; ++dt)
            #pragma unroll
            for (int r = 0; r < 4; ++r) {
                const size_t idx = (size_t)(b * 2048 + orow + r) * 1024 + h * 64 + dt * 16 + t;
                y[idx] = f2b(accO[dt][r] / lSum[r]);
            }
    }
}

extern "C" void kernel_launch(void* const* d_in, const int* in_sizes, int n_in,
                              void* d_out, int out_size, void* d_ws, size_t ws_size,
                              hipStream_t stream) {
    const float* x     = (const float*)d_in[0];
    const int*   ym    = (const int*)d_in[1];
    const float* Wqkv  = (const float*)d_in[2];
    const float* Wattn = (const float*)d_in[3];
    const float* s1    = (const float*)d_in[4];
    const float* s2    = (const float*)d_in[5];
    const float* Wfc1  = (const float*)d_in[6];
    const float* Wfc2  = (const float*)d_in[7];
    const float* Wmlp  = (const float*)d_in[8];

    char* ws = (char*)d_ws;
    u16*    h    = (u16*)(ws + 0);          // 8 MB bf16; reused as attention output
    u16*    qkv  = (u16*)(ws + 8388608);    // 24 MB bf16; later reused as fc1/m
    u16*    fc1  = qkv;
    float*  xr   = (float*)(ws + 33554432); // 16 MB fp32 residual
    u16*    WtA  = (u16*)(ws + 50331648);   // 2 MB
    u16*    WtF1 = (u16*)(ws + 52428800);   // 5.5 MB
    u16*    WtF2 = (u16*)(ws + 58195968);   // 5.5 MB
    u16*    WtM  = (u16*)(ws + 63963136);   // 5.5 MB
    u16*    WtQ  = (u16*)(ws + 73400320);   // 6 MB
    const dim3 tb(32, 8);

    prep_kernel<<<16640, tb, 0, stream>>>(Wqkv, Wattn, Wfc1, Wfc2, Wmlp,
                                          WtQ, WtA, WtF1, WtF2, WtM, x, s1, h);
    gemm_bt<0><<<dim3(24, 32), 256, 0, stream>>>(h, WtQ, qkv, nullptr, 3072, 1024);
    rope_kernel<<<512, 256, 0, stream>>>(qkv);
    attn_kernel<<<512, 256, 0, stream>>>(qkv, ym, h);   // h dead -> y
    gemm_bt64<1><<<dim3(16, 32), 256, 0, stream>>>(h, WtA, xr, x, 1024, 1024);
    rmsnorm_f32<<<4096, 256, 0, stream>>>(xr, s2, h);
    gemm_fc<<<dim3(44, 32), 256, 0, stream>>>(h, WtF1, WtF2, fc1, 2816, 1024);
    gemm_bt64<1><<<dim3(16, 32), 256, 0, stream>>>(fc1, WtM, (float*)d_out, xr, 1024, 2816);
}

// Round 12
// 355.100 us; speedup vs baseline: 1.0417x; 1.0112x over previous
//
#include <hip/hip_runtime.h>
#include <stdint.h>

typedef unsigned short u16;
typedef __attribute__((ext_vector_type(8))) short bf16x8;
typedef __attribute__((ext_vector_type(4))) float f32x4;

__device__ __forceinline__ float b2f(u16 u) {
    union { float f; uint32_t u; } v; v.u = ((uint32_t)u) << 16; return v.f;
}
__device__ __forceinline__ u16 f2b(float f) {
    union { float f; uint32_t u; } v; v.f = f;
    uint32_t r = v.u + 0x7FFFu + ((v.u >> 16) & 1u);
    return (u16)(r >> 16);
}
// HW packed f32->bf16 (RNE): 2 values in 1 instruction (no builtin on gfx950)
__device__ __forceinline__ uint32_t cvt_pk_bf16(float lo, float hi) {
    uint32_t r;
    asm("v_cvt_pk_bf16_f32 %0, %1, %2" : "=v"(r) : "v"(lo), "v"(hi));
    return r;
}

// DPP cross-lane move within 16-lane rows (row_ror:N = 0x120+N). Full-rate VALU.
template <int CTRL>
__device__ __forceinline__ float dppf(float x) {
    union { float f; int i; } u; u.f = x;
    u.i = __builtin_amdgcn_update_dpp(0, u.i, CTRL, 0xF, 0xF, false);
    return u.f;
}
// all-lanes max/sum over each 16-lane DPP row via rotate-reduce
__device__ __forceinline__ float rowmax16(float v) {
    v = fmaxf(v, dppf<0x121>(v));   // ror 1
    v = fmaxf(v, dppf<0x122>(v));   // ror 2
    v = fmaxf(v, dppf<0x124>(v));   // ror 4
    v = fmaxf(v, dppf<0x128>(v));   // ror 8
    return v;
}
__device__ __forceinline__ float rowsum16(float v) {
    v += dppf<0x121>(v);
    v += dppf<0x122>(v);
    v += dppf<0x124>(v);
    v += dppf<0x128>(v);
    return v;
}

// async global->LDS, 16B/lane. LDS dest must be wave-uniform; HW adds lane*16.
__device__ __forceinline__ void stage16(const void* g, void* l) {
    __builtin_amdgcn_global_load_lds(
        (const __attribute__((address_space(1))) uint32_t*)(uintptr_t)g,
        (__attribute__((address_space(3))) uint32_t*)(uint32_t)(uintptr_t)l,
        16, 0, 0);
}

// ---- fused preprocessing: 5 weight transposes + rmsnorm1, ONE launch ----
// blocks 0..12543: transpose tiles; blocks 12544..16639: rmsnorm rows.
__global__ __launch_bounds__(256) void prep_kernel(const float* __restrict__ Wqkv,
                                                   const float* __restrict__ Wattn,
                                                   const float* __restrict__ Wfc1,
                                                   const float* __restrict__ Wfc2,
                                                   const float* __restrict__ Wmlp,
                                                   u16* WtQ, u16* WtA, u16* WtF1,
                                                   u16* WtF2, u16* WtM,
                                                   const float* __restrict__ xin,
                                                   const float* __restrict__ scale,
                                                   u16* __restrict__ xout) {
    const int tx = threadIdx.x, ty = threadIdx.y; // 32 x 8
    int id = blockIdx.x;
    if (id >= 12544) {
        // ---- rmsnorm path ----
        const int row = id - 12544, tid = ty * 32 + tx;
        const float4 v = ((const float4*)(xin + (size_t)row * 1024))[tid];
        float ss = v.x * v.x + v.y * v.y + v.z * v.z + v.w * v.w;
        #pragma unroll
        for (int d = 32; d; d >>= 1) ss += __shfl_xor(ss, d);
        __shared__ float wsum[4];
        if ((tid & 63) == 0) wsum[tid >> 6] = ss;
        __syncthreads();
        const float r = rsqrtf((wsum[0] + wsum[1] + wsum[2] + wsum[3]) * (1.f / 1024.f) + 1e-5f);
        const float4 sc = ((const float4*)scale)[tid];
        uint2 o;
        o.x = cvt_pk_bf16(v.x * sc.x * r, v.y * sc.y * r);
        o.y = cvt_pk_bf16(v.z * sc.z * r, v.w * sc.w * r);
        ((uint2*)(xout + (size_t)row * 1024))[tid] = o;
        return;
    }
    // ---- transpose path ----
    __shared__ u16 tile[32][33];
    const float* src; u16* dst; int R, C;
    if (id < 3072)      {             src = Wqkv;  dst = WtQ;  R = 1024; C = 3072; }
    else if (id < 4096) { id -= 3072; src = Wattn; dst = WtA;  R = 1024; C = 1024; }
    else if (id < 6912) { id -= 4096; src = Wfc1;  dst = WtF1; R = 1024; C = 2816; }
    else if (id < 9728) { id -= 6912; src = Wfc2;  dst = WtF2; R = 1024; C = 2816; }
    else                { id -= 9728; src = Wmlp;  dst = WtM;  R = 2816; C = 1024; }
    const int nbx = C >> 5;
    const int bx = id % nbx, by = id / nbx;
    const int cx = bx * 32, ry = by * 32;
    #pragma unroll
    for (int i = 0; i < 32; i += 8)
        tile[ty + i][tx] = f2b(src[(size_t)(ry + ty + i) * C + cx + tx]);
    __syncthreads();
    #pragma unroll
    for (int i = 0; i < 32; i += 8)
        dst[(size_t)(cx + ty + i) * R + ry + tx] = tile[tx][ty + i];
}

// ---- rmsnorm (row = 1024): fp32 in, fp32 scale, bf16 out ----
__global__ __launch_bounds__(256) void rmsnorm_f32(const float* __restrict__ xin,
                                                   const float* __restrict__ scale,
                                                   u16* __restrict__ out) {
    const int row = blockIdx.x, tid = threadIdx.x;
    const float4 v = ((const float4*)(xin + (size_t)row * 1024))[tid];
    float ss = v.x * v.x + v.y * v.y + v.z * v.z + v.w * v.w;
    #pragma unroll
    for (int d = 32; d; d >>= 1) ss += __shfl_xor(ss, d);
    __shared__ float wsum[4];
    if ((tid & 63) == 0) wsum[tid >> 6] = ss;
    __syncthreads();
    const float r = rsqrtf((wsum[0] + wsum[1] + wsum[2] + wsum[3]) * (1.f / 1024.f) + 1e-5f);
    const float4 sc = ((const float4*)scale)[tid];
    uint2 o;
    o.x = cvt_pk_bf16(v.x * sc.x * r, v.y * sc.y * r);
    o.y = cvt_pk_bf16(v.z * sc.z * r, v.w * sc.w * r);
    ((uint2*)(out + (size_t)row * 1024))[tid] = o;
}

// ---- RoPE in place on q,k thirds of qkv (4096 x 3072 bf16) ----
// One thread per (row, i): trig computed ONCE, applied to 16 q-heads + 16 k-heads
// via coalesced u32 accesses (lanes 0..31 span i -> 128B contiguous per head).
__global__ __launch_bounds__(256) void rope_kernel(u16* __restrict__ qkv) {
    const int gid = blockIdx.x * 256 + threadIdx.x;  // 131072 = 4096 rows * 32 i
    const int i = gid & 31;
    const int row = gid >> 5;
    const int tpos = row & 2047;
    const float theta = expf(-(float)i * (9.210340371976184f / 32.0f));
    const float ang = (float)tpos * theta;
    const float c = cosf(ang), s = sinf(ang);
    uint32_t* p = (uint32_t*)qkv + (size_t)row * 1536 + i;
    #pragma unroll
    for (int h = 0; h < 16; ++h) {
        const uint32_t uq = p[h * 32];
        {
            const float xe = b2f((u16)(uq & 0xffff)), xo = b2f((u16)(uq >> 16));
            p[h * 32] = cvt_pk_bf16(xe * c - xo * s, xe * s + xo * c);
        }
        const uint32_t uk = p[512 + h * 32];
        {
            const float xe = b2f((u16)(uk & 0xffff)), xo = b2f((u16)(uk >> 16));
            p[512 + h * 32] = cvt_pk_bf16(xe * c - xo * s, xe * s + xo * c);
        }
    }
}

// ---- GEMM: A (M x K) bf16, Bt (N x K) bf16, 128x128 tile, 2x BK=32 halves per
// barrier pair. Default block mapping (R11's XCD remap cost ~8us: GEMM drain is
// not HBM-latency-sensitive; remap hurt C-write locality).
// EPI 0: Cbf16; EPI 1: Cf32 = acc + Res_f32
template <int EPI>
__global__ __launch_bounds__(256) void gemm_bt(const u16* __restrict__ A,
                                               const u16* __restrict__ Bt,
                                               void* __restrict__ Cout,
                                               const void* __restrict__ Res,
                                               int N, int K) {
    __shared__ __attribute__((aligned(16))) u16 As[2][128 * 32];
    __shared__ __attribute__((aligned(16))) u16 Bs[2][128 * 32];
    const int tid = threadIdx.x;
    const int w = tid >> 6, lane = tid & 63;
    const int quad = lane >> 4, t = lane & 15;
    const int m0 = blockIdx.y * 128, n0 = blockIdx.x * 128;
    const int wm = (w >> 1) * 64, wn = (w & 1) * 64;

    const int srow = w * 16 + (lane >> 2);
    const int scol = (lane & 3) * 8;
    const u16* pA0 = A + (size_t)(m0 + srow) * K + scol;
    const u16* pA1 = pA0 + (size_t)64 * K;
    const u16* pB0 = Bt + (size_t)(n0 + srow) * K + scol;
    const u16* pB1 = pB0 + (size_t)64 * K;

    f32x4 acc[4][4];
    #pragma unroll
    for (int i = 0; i < 4; ++i)
        #pragma unroll
        for (int j = 0; j < 4; ++j) acc[i][j] = (f32x4){0.f, 0.f, 0.f, 0.f};

    for (int kb = 0; kb < K; kb += 64) {
        __syncthreads();                 // prior iteration's LDS reads complete
        stage16(pA0 + kb,      (char*)As[0] + w * 1024);
        stage16(pA1 + kb,      (char*)As[0] + 4096 + w * 1024);
        stage16(pB0 + kb,      (char*)Bs[0] + w * 1024);
        stage16(pB1 + kb,      (char*)Bs[0] + 4096 + w * 1024);
        stage16(pA0 + kb + 32, (char*)As[1] + w * 1024);
        stage16(pA1 + kb + 32, (char*)As[1] + 4096 + w * 1024);
        stage16(pB0 + kb + 32, (char*)Bs[1] + w * 1024);
        stage16(pB1 + kb + 32, (char*)Bs[1] + 4096 + w * 1024);
        __syncthreads();                 // vmcnt(0) drain: staging visible
        #pragma unroll
        for (int hf = 0; hf < 2; ++hf) {
            bf16x8 af[4], bfr[4];
            #pragma unroll
            for (int mi = 0; mi < 4; ++mi)
                af[mi] = *(const bf16x8*)((char*)As[hf] + (wm + mi * 16 + t) * 64 + quad * 16);
            #pragma unroll
            for (int ni = 0; ni < 4; ++ni)
                bfr[ni] = *(const bf16x8*)((char*)Bs[hf] + (wn + ni * 16 + t) * 64 + quad * 16);
            #pragma unroll
            for (int mi = 0; mi < 4; ++mi)
                #pragma unroll
                for (int ni = 0; ni < 4; ++ni)
                    acc[mi][ni] = __builtin_amdgcn_mfma_f32_16x16x32_bf16(af[mi], bfr[ni],
                                                                         acc[mi][ni], 0, 0, 0);
        }
    }
    #pragma unroll
    for (int mi = 0; mi < 4; ++mi) {
        const int row0 = m0 + wm + mi * 16 + quad * 4;
        #pragma unroll
        for (int ni = 0; ni < 4; ++ni) {
            const int col = n0 + wn + ni * 16 + t;
            #pragma unroll
            for (int r = 0; r < 4; r += 2) {
                const size_t idx0 = (size_t)(row0 + r) * N + col;
                const size_t idx1 = (size_t)(row0 + r + 1) * N + col;
                if (EPI == 0) {
                    const uint32_t pk2 = cvt_pk_bf16(acc[mi][ni][r], acc[mi][ni][r + 1]);
                    ((u16*)Cout)[idx0] = (u16)pk2;
                    ((u16*)Cout)[idx1] = (u16)(pk2 >> 16);
                } else {
                    ((float*)Cout)[idx0] = acc[mi][ni][r]     + ((const float*)Res)[idx0];
                    ((float*)Cout)[idx1] = acc[mi][ni][r + 1] + ((const float*)Res)[idx1];
                }
            }
        }
    }
}

// ---- GEMM variant: 128x64 tile for N=1024 shapes (512 blocks -> 2 blocks/CU) ----
template <int EPI>
__global__ __launch_bounds__(256) void gemm_bt64(const u16* __restrict__ A,
                                                 const u16* __restrict__ Bt,
                                                 void* __restrict__ Cout,
                                                 const float* __restrict__ Res,
                                                 int N, int K) {
    __shared__ __attribute__((aligned(16))) u16 As[2][128 * 32];  // 16 KB
    __shared__ __attribute__((aligned(16))) u16 Bs[2][64 * 32];   // 8 KB
    const int tid = threadIdx.x;
    const int w = tid >> 6, lane = tid & 63;
    const int quad = lane >> 4, t = lane & 15;
    const int m0 = blockIdx.y * 128, n0 = blockIdx.x * 64;
    const int wm = (w >> 1) * 64, wn = (w & 1) * 32;

    const int srow = w * 16 + (lane >> 2);
    const int scol = (lane & 3) * 8;
    const u16* pA0 = A + (size_t)(m0 + srow) * K + scol;
    const u16* pA1 = pA0 + (size_t)64 * K;
    const u16* pB0 = Bt + (size_t)(n0 + srow) * K + scol;

    f32x4 acc[4][2];
    #pragma unroll
    for (int i = 0; i < 4; ++i)
        #pragma unroll
        for (int j = 0; j < 2; ++j) acc[i][j] = (f32x4){0.f, 0.f, 0.f, 0.f};

    for (int kb = 0; kb < K; kb += 64) {
        __syncthreads();
        stage16(pA0 + kb,      (char*)As[0] + w * 1024);
        stage16(pA1 + kb,      (char*)As[0] + 4096 + w * 1024);
        stage16(pB0 + kb,      (char*)Bs[0] + w * 1024);
        stage16(pA0 + kb + 32, (char*)As[1] + w * 1024);
        stage16(pA1 + kb + 32, (char*)As[1] + 4096 + w * 1024);
        stage16(pB0 + kb + 32, (char*)Bs[1] + w * 1024);
        __syncthreads();
        #pragma unroll
        for (int hf = 0; hf < 2; ++hf) {
            bf16x8 af[4], bfr[2];
            #pragma unroll
            for (int mi = 0; mi < 4; ++mi)
                af[mi] = *(const bf16x8*)((char*)As[hf] + (wm + mi * 16 + t) * 64 + quad * 16);
            #pragma unroll
            for (int ni = 0; ni < 2; ++ni)
                bfr[ni] = *(const bf16x8*)((char*)Bs[hf] + (wn + ni * 16 + t) * 64 + quad * 16);
            #pragma unroll
            for (int mi = 0; mi < 4; ++mi)
                #pragma unroll
                for (int ni = 0; ni < 2; ++ni)
                    acc[mi][ni] = __builtin_amdgcn_mfma_f32_16x16x32_bf16(af[mi], bfr[ni],
                                                                         acc[mi][ni], 0, 0, 0);
        }
    }
    #pragma unroll
    for (int mi = 0; mi < 4; ++mi) {
        const int row0 = m0 + wm + mi * 16 + quad * 4;
        #pragma unroll
        for (int ni = 0; ni < 2; ++ni) {
            const int col = n0 + wn + ni * 16 + t;
            #pragma unroll
            for (int r = 0; r < 4; ++r) {
                const size_t idx = (size_t)(row0 + r) * N + col;
                const float v = acc[mi][ni][r];
                if (EPI == 0) ((u16*)Cout)[idx]   = f2b(v);
                else          ((float*)Cout)[idx] = v + Res[idx];
            }
        }
    }
}

// ---- FUSED fc1+fc2 GEMM: A (M x K), B1t/B2t (N x K); C = silu(A@W1) * (A@W2).
// A staged ONCE for both B operands; silu-mul in-register; one dispatch.
__global__ __launch_bounds__(256) void gemm_fc(const u16* __restrict__ A,
                                               const u16* __restrict__ B1t,
                                               const u16* __restrict__ B2t,
                                               u16* __restrict__ Cout,
                                               int N, int K) {
    __shared__ __attribute__((aligned(16))) u16 As[2][128 * 32];   // 16 KB
    __shared__ __attribute__((aligned(16))) u16 B1s[2][64 * 32];   // 8 KB
    __shared__ __attribute__((aligned(16))) u16 B2s[2][64 * 32];   // 8 KB
    const int tid = threadIdx.x;
    const int w = tid >> 6, lane = tid & 63;
    const int quad = lane >> 4, t = lane & 15;
    const int m0 = blockIdx.y * 128, n0 = blockIdx.x * 64;
    const int wm = (w >> 1) * 64, wn = (w & 1) * 32;

    const int srow = w * 16 + (lane >> 2);
    const int scol = (lane & 3) * 8;
    const u16* pA0 = A + (size_t)(m0 + srow) * K + scol;
    const u16* pA1 = pA0 + (size_t)64 * K;
    const u16* pB1 = B1t + (size_t)(n0 + srow) * K + scol;
    const u16* pB2 = B2t + (size_t)(n0 + srow) * K + scol;

    f32x4 acc1[4][2], acc2[4][2];
    #pragma unroll
    for (int i = 0; i < 4; ++i)
        #pragma unroll
        for (int j = 0; j < 2; ++j) {
            acc1[i][j] = (f32x4){0.f, 0.f, 0.f, 0.f};
            acc2[i][j] = (f32x4){0.f, 0.f, 0.f, 0.f};
        }

    for (int kb = 0; kb < K; kb += 64) {
        __syncthreads();
        stage16(pA0 + kb,      (char*)As[0] + w * 1024);
        stage16(pA1 + kb,      (char*)As[0] + 4096 + w * 1024);
        stage16(pB1 + kb,      (char*)B1s[0] + w * 1024);
        stage16(pB2 + kb,      (char*)B2s[0] + w * 1024);
        stage16(pA0 + kb + 32, (char*)As[1] + w * 1024);
        stage16(pA1 + kb + 32, (char*)As[1] + 4096 + w * 1024);
        stage16(pB1 + kb + 32, (char*)B1s[1] + w * 1024);
        stage16(pB2 + kb + 32, (char*)B2s[1] + w * 1024);
        __syncthreads();
        #pragma unroll
        for (int hf = 0; hf < 2; ++hf) {
            bf16x8 af[4], b1r[2], b2r[2];
            #pragma unroll
            for (int mi = 0; mi < 4; ++mi)
                af[mi] = *(const bf16x8*)((char*)As[hf] + (wm + mi * 16 + t) * 64 + quad * 16);
            #pragma unroll
            for (int ni = 0; ni < 2; ++ni) {
                b1r[ni] = *(const bf16x8*)((char*)B1s[hf] + (wn + ni * 16 + t) * 64 + quad * 16);
                b2r[ni] = *(const bf16x8*)((char*)B2s[hf] + (wn + ni * 16 + t) * 64 + quad * 16);
            }
            #pragma unroll
            for (int mi = 0; mi < 4; ++mi)
                #pragma unroll
                for (int ni = 0; ni < 2; ++ni) {
                    acc1[mi][ni] = __builtin_amdgcn_mfma_f32_16x16x32_bf16(af[mi], b1r[ni],
                                                                          acc1[mi][ni], 0, 0, 0);
                    acc2[mi][ni] = __builtin_amdgcn_mfma_f32_16x16x32_bf16(af[mi], b2r[ni],
                                                                          acc2[mi][ni], 0, 0, 0);
                }
        }
    }
    #pragma unroll
    for (int mi = 0; mi < 4; ++mi) {
        const int row0 = m0 + wm + mi * 16 + quad * 4;
        #pragma unroll
        for (int ni = 0; ni < 2; ++ni) {
            const int col = n0 + wn + ni * 16 + t;
            float mv[4];
            #pragma unroll
            for (int r = 0; r < 4; ++r) {
                const float a = acc1[mi][ni][r];
                mv[r] = (a / (1.f + __expf(-a))) * acc2[mi][ni][r];
            }
            #pragma unroll
            for (int r = 0; r < 4; r += 2) {
                const uint32_t pk2 = cvt_pk_bf16(mv[r], mv[r + 1]);
                Cout[(size_t)(row0 + r) * N + col]     = (u16)pk2;
                Cout[(size_t)(row0 + r + 1) * N + col] = (u16)(pk2 >> 16);
            }
        }
    }
}

// ---- flash attention: qkv (4096 x 3072 bf16, roped), y (4096 x 1024 bf16) ----
// KVBLK=128: two 64-key tiles per iteration. Grid = 512 blocks = 2/CU, so the
// ~53 KB LDS is free (occupancy grid-limited, not LDS-limited). Halves barrier
// drains (17 iters vs 33) and per-iteration softmax fixed costs. Pairing stays
// uniform: ceil((32-k)/2) + ceil((k+1)/2) = 17 for all k. XCD-grouped mapping;
// DPP softmax; last-iteration-only mask; folded Q-scale; Vts XOR-swizzled.
__global__ __launch_bounds__(256) void attn_kernel(const u16* __restrict__ qkv,
                                                   const int* __restrict__ ymask,
                                                   u16* __restrict__ y) {
    const int gid = blockIdx.x;              // 0..511
    const int xcd = gid & 7;
    const int j2 = gid >> 3;                 // 0..63
    const int slot = j2 >> 4;                // 0..3
    const int pairk = j2 & 15;               // 0..15
    const int group = slot * 8 + xcd;        // 0..31
    const int h = group & 15, b = group >> 4;
    const int tid = threadIdx.x;
    const int w = tid >> 6, lane = tid & 63;
    const int quad = lane >> 4, t = lane & 15;

    __shared__ __attribute__((aligned(16))) u16 Ks[128 * 72];    // [key][d], 144B rows, 18KB
    __shared__ __attribute__((aligned(16))) u16 Vts[64 * 136];   // [d][key], 272B rows, 17KB
    __shared__ __attribute__((aligned(16))) u16 Ps[4][16 * 136]; // per-wave P [m][key], 17KB
    __shared__ int ymL[64];
    if (pairk == 0 && tid < 64) ymL[tid] = ymask[b * 64 + tid];

    // staging assignment: thread -> (keys skey+32c, dg = tid&7)
    const int skey = tid >> 3, sdg = tid & 7;
    const u16* pK = qkv + (size_t)(b * 2048 + skey) * 3072 + h * 64 + sdg * 8 + 1024;

    for (int seg = 0; seg < 2; ++seg) {
        const int qt = seg ? pairk : 31 - pairk;  // long segment first
        const int q0 = qt * 64;
        const int nit = (qt >> 1) + 1;            // 128-key tiles covering keys 0..qt*64+63

        bf16x8 aQ[2];
        {
            const u16* qp = qkv + (size_t)(b * 2048 + q0 + w * 16 + t) * 3072 + h * 64 + quad * 8;
            aQ[0] = *(const bf16x8*)qp;
            aQ[1] = *(const bf16x8*)(qp + 32);
            #pragma unroll
            for (int i = 0; i < 8; ++i) {   // fold 1/sqrt(64): *2^-3 exact in bf16
                aQ[0][i] = (short)f2b(b2f((u16)aQ[0][i]) * 0.125f);
                aQ[1][i] = (short)f2b(b2f((u16)aQ[1][i]) * 0.125f);
            }
        }

        f32x4 accO[4] = {(f32x4){0,0,0,0},(f32x4){0,0,0,0},(f32x4){0,0,0,0},(f32x4){0,0,0,0}};
        float mOld[4] = {-INFINITY, -INFINITY, -INFINITY, -INFINITY};
        float lSum[4] = {0.f, 0.f, 0.f, 0.f};

        for (int kb = 0; kb < nit; ++kb) {
            // global loads issued before the barrier (latency overlaps drain)
            const u16* pk = pK + (size_t)kb * 393216;        // kb*128*3072
            uint4 kv[4], vv[4];
            #pragma unroll
            for (int c = 0; c < 4; ++c) {
                kv[c] = *(const uint4*)(pk + (size_t)c * 98304);          // +c*32*3072
                vv[c] = *(const uint4*)(pk + (size_t)c * 98304 + 1024);
            }
            __syncthreads();                 // prior iteration's LDS reads done
            #pragma unroll
            for (int c = 0; c < 4; ++c)
                *(uint4*)((char*)Ks + (skey + 32 * c) * 144 + sdg * 16) = kv[c];
            #pragma unroll
            for (int c = 0; c < 4; ++c) {
                const u16* vp = (const u16*)&vv[c];
                const int blk = ((skey >> 3) + 4 * c) ^ sdg;
                #pragma unroll
                for (int jj = 0; jj < 8; ++jj) {
                    const int row = sdg * 8 + jj;
                    Vts[row * 136 + blk * 8 + (skey & 7)] = vp[jj];
                }
            }
            __syncthreads();

            float s[8][4];
            __builtin_amdgcn_s_setprio(1);
            #pragma unroll
            for (int ni = 0; ni < 8; ++ni) {
                bf16x8 bK0 = *(const bf16x8*)((char*)Ks + (ni * 16 + t) * 144 + quad * 16);
                bf16x8 bK1 = *(const bf16x8*)((char*)Ks + (ni * 16 + t) * 144 + 64 + quad * 16);
                f32x4 sa = (f32x4){0.f, 0.f, 0.f, 0.f};
                sa = __builtin_amdgcn_mfma_f32_16x16x32_bf16(aQ[0], bK0, sa, 0, 0, 0);
                sa = __builtin_amdgcn_mfma_f32_16x16x32_bf16(aQ[1], bK1, sa, 0, 0, 0);
                #pragma unroll
                for (int r = 0; r < 4; ++r) s[ni][r] = sa[r];
            }
            __builtin_amdgcn_s_setprio(0);

            // mask only on the last iteration (covers the diagonal; for even qt the
            // upper half-tile is fully masked). ym text-mask only in qt==0, j<64.
            if (kb == nit - 1) {
                const int irow = q0 + w * 16 + quad * 4;
                #pragma unroll
                for (int ni = 0; ni < 8; ++ni)
                    #pragma unroll
                    for (int r = 0; r < 4; ++r) {
                        const int i = irow + r, j = kb * 128 + ni * 16 + t;
                        const bool ok = (j <= i) ||
                                        (qt == 0 && j < 64 && ymL[i & 63] && ymL[j]);
                        if (!ok) s[ni][r] = -INFINITY;
                    }
            }

            float alpha[4];
            bool upd = false;
            #pragma unroll
            for (int r = 0; r < 4; ++r) {
                float mt = fmaxf(fmaxf(fmaxf(s[0][r], s[1][r]), fmaxf(s[2][r], s[3][r])),
                                 fmaxf(fmaxf(s[4][r], s[5][r]), fmaxf(s[6][r], s[7][r])));
                mt = rowmax16(mt);                       // DPP, VALU-rate
                const float mNew = fmaxf(mOld[r], mt);
                upd = upd || (mNew > mOld[r]);
                alpha[r] = __expf(mOld[r] - mNew);
                #pragma unroll
                for (int ni = 0; ni < 8; ++ni) s[ni][r] = __expf(s[ni][r] - mNew);
                mOld[r] = mNew;
            }

            // P (C-layout) -> per-wave LDS, issued early; ds_write latency hides
            // under the DPP sum-reduces below. Same-wave, no barrier needed.
            u16* Pw = Ps[w];
            #pragma unroll
            for (int ni = 0; ni < 8; ++ni)
                #pragma unroll
                for (int r = 0; r < 4; ++r)
                    Pw[(quad * 4 + r) * 136 + ni * 16 + t] = f2b(s[ni][r]);

            #pragma unroll
            for (int r = 0; r < 4; ++r) {
                float rs = ((s[0][r] + s[1][r]) + (s[2][r] + s[3][r])) +
                           ((s[4][r] + s[5][r]) + (s[6][r] + s[7][r]));
                rs = rowsum16(rs);                       // DPP, VALU-rate
                lSum[r] = lSum[r] * alpha[r] + rs;
            }
            if (__any(upd)) {               // skip O-rescale when no row's max moved
                #pragma unroll
                for (int dt = 0; dt < 4; ++dt)
                    #pragma unroll
                    for (int r = 0; r < 4; ++r) accO[dt][r] *= alpha[r];
            }

            bf16x8 aP[4];
            #pragma unroll
            for (int c = 0; c < 4; ++c)
                aP[c] = *(const bf16x8*)((char*)Pw + t * 272 + c * 64 + quad * 16);
            __builtin_amdgcn_s_setprio(1);
            #pragma unroll
            for (int dt = 0; dt < 4; ++dt) {
                const int row = dt * 16 + t, rb = row >> 3;
                #pragma unroll
                for (int c = 0; c < 4; ++c) {
                    bf16x8 bV = *(const bf16x8*)((char*)Vts + row * 272 +
                                                 ((((skey & -64) * 0 + 4 * c + quad) ^ rb) << 4));
                    accO[dt] = __builtin_amdgcn_mfma_f32_16x16x32_bf16(aP[c], bV,
                                                                      accO[dt], 0, 0, 0);
                }
            }
            __builtin_amdgcn_s_setprio(0);
        }
        const int orow = q0 + w * 16 + quad * 4;
        #pragma unroll
        for (int dt = 0; dt < 4; ++dt)
            #pragma unroll
            for (int r = 0; r < 4; ++r) {
                const size_t idx = (size_t)(b * 2048 + orow + r) * 1024 + h * 64 + dt * 16 + t;
                y[idx] = f2b(accO[dt][r] / lSum[r]);
            }
    }
}

extern "C" void kernel_launch(void* const* d_in, const int* in_sizes, int n_in,
                              void* d_out, int out_size, void* d_ws, size_t ws_size,
                              hipStream_t stream) {
    const float* x     = (const float*)d_in[0];
    const int*   ym    = (const int*)d_in[1];
    const float* Wqkv  = (const float*)d_in[2];
    const float* Wattn = (const float*)d_in[3];
    const float* s1    = (const float*)d_in[4];
    const float* s2    = (const float*)d_in[5];
    const float* Wfc1  = (const float*)d_in[6];
    const float* Wfc2  = (const float*)d_in[7];
    const float* Wmlp  = (const float*)d_in[8];

    char* ws = (char*)d_ws;
    u16*    h    = (u16*)(ws + 0);          // 8 MB bf16; reused as attention output
    u16*    qkv  = (u16*)(ws + 8388608);    // 24 MB bf16; later reused as fc1/m
    u16*    fc1  = qkv;
    float*  xr   = (float*)(ws + 33554432); // 16 MB fp32 residual
    u16*    WtA  = (u16*)(ws + 50331648);   // 2 MB
    u16*    WtF1 = (u16*)(ws + 52428800);   // 5.5 MB
    u16*    WtF2 = (u16*)(ws + 58195968);   // 5.5 MB
    u16*    WtM  = (u16*)(ws + 63963136);   // 5.5 MB
    u16*    WtQ  = (u16*)(ws + 73400320);   // 6 MB
    const dim3 tb(32, 8);

    prep_kernel<<<16640, tb, 0, stream>>>(Wqkv, Wattn, Wfc1, Wfc2, Wmlp,
                                          WtQ, WtA, WtF1, WtF2, WtM, x, s1, h);
    gemm_bt<0><<<dim3(24, 32), 256, 0, stream>>>(h, WtQ, qkv, nullptr, 3072, 1024);
    rope_kernel<<<512, 256, 0, stream>>>(qkv);
    attn_kernel<<<512, 256, 0, stream>>>(qkv, ym, h);   // h dead -> y
    gemm_bt64<1><<<dim3(16, 32), 256, 0, stream>>>(h, WtA, xr, x, 1024, 1024);
    rmsnorm_f32<<<4096, 256, 0, stream>>>(xr, s2, h);
    gemm_fc<<<dim3(44, 32), 256, 0, stream>>>(h, WtF1, WtF2, fc1, 2816, 1024);
    gemm_bt64<1><<<dim3(16, 32), 256, 0, stream>>>(fc1, WtM, (float*)d_out, xr, 1024, 2816);
}

// Round 13
// 347.826 us; speedup vs baseline: 1.0635x; 1.0209x over previous
//
#include <hip/hip_runtime.h>
#include <stdint.h>

typedef unsigned short u16;
typedef __attribute__((ext_vector_type(8))) short bf16x8;
typedef __attribute__((ext_vector_type(4))) float f32x4;

__device__ __forceinline__ float b2f(u16 u) {
    union { float f; uint32_t u; } v; v.u = ((uint32_t)u) << 16; return v.f;
}
__device__ __forceinline__ u16 f2b(float f) {
    union { float f; uint32_t u; } v; v.f = f;
    uint32_t r = v.u + 0x7FFFu + ((v.u >> 16) & 1u);
    return (u16)(r >> 16);
}
// HW packed f32->bf16 (RNE): 2 values in 1 instruction (no builtin on gfx950)
__device__ __forceinline__ uint32_t cvt_pk_bf16(float lo, float hi) {
    uint32_t r;
    asm("v_cvt_pk_bf16_f32 %0, %1, %2" : "=v"(r) : "v"(lo), "v"(hi));
    return r;
}

// DPP cross-lane move within 16-lane rows (row_ror:N = 0x120+N). Full-rate VALU.
template <int CTRL>
__device__ __forceinline__ float dppf(float x) {
    union { float f; int i; } u; u.f = x;
    u.i = __builtin_amdgcn_update_dpp(0, u.i, CTRL, 0xF, 0xF, false);
    return u.f;
}
// all-lanes max/sum over each 16-lane DPP row via rotate-reduce
__device__ __forceinline__ float rowmax16(float v) {
    v = fmaxf(v, dppf<0x121>(v));   // ror 1
    v = fmaxf(v, dppf<0x122>(v));   // ror 2
    v = fmaxf(v, dppf<0x124>(v));   // ror 4
    v = fmaxf(v, dppf<0x128>(v));   // ror 8
    return v;
}
__device__ __forceinline__ float rowsum16(float v) {
    v += dppf<0x121>(v);
    v += dppf<0x122>(v);
    v += dppf<0x124>(v);
    v += dppf<0x128>(v);
    return v;
}

// async global->LDS, 16B/lane. LDS dest must be wave-uniform; HW adds lane*16.
__device__ __forceinline__ void stage16(const void* g, void* l) {
    __builtin_amdgcn_global_load_lds(
        (const __attribute__((address_space(1))) uint32_t*)(uintptr_t)g,
        (__attribute__((address_space(3))) uint32_t*)(uint32_t)(uintptr_t)l,
        16, 0, 0);
}

// ---- fused preprocessing: 5 weight transposes + rmsnorm1, ONE launch ----
// blocks 0..12543: transpose tiles; blocks 12544..16639: rmsnorm rows.
__global__ __launch_bounds__(256) void prep_kernel(const float* __restrict__ Wqkv,
                                                   const float* __restrict__ Wattn,
                                                   const float* __restrict__ Wfc1,
                                                   const float* __restrict__ Wfc2,
                                                   const float* __restrict__ Wmlp,
                                                   u16* WtQ, u16* WtA, u16* WtF1,
                                                   u16* WtF2, u16* WtM,
                                                   const float* __restrict__ xin,
                                                   const float* __restrict__ scale,
                                                   u16* __restrict__ xout) {
    const int tx = threadIdx.x, ty = threadIdx.y; // 32 x 8
    int id = blockIdx.x;
    if (id >= 12544) {
        // ---- rmsnorm path ----
        const int row = id - 12544, tid = ty * 32 + tx;
        const float4 v = ((const float4*)(xin + (size_t)row * 1024))[tid];
        float ss = v.x * v.x + v.y * v.y + v.z * v.z + v.w * v.w;
        #pragma unroll
        for (int d = 32; d; d >>= 1) ss += __shfl_xor(ss, d);
        __shared__ float wsum[4];
        if ((tid & 63) == 0) wsum[tid >> 6] = ss;
        __syncthreads();
        const float r = rsqrtf((wsum[0] + wsum[1] + wsum[2] + wsum[3]) * (1.f / 1024.f) + 1e-5f);
        const float4 sc = ((const float4*)scale)[tid];
        uint2 o;
        o.x = cvt_pk_bf16(v.x * sc.x * r, v.y * sc.y * r);
        o.y = cvt_pk_bf16(v.z * sc.z * r, v.w * sc.w * r);
        ((uint2*)(xout + (size_t)row * 1024))[tid] = o;
        return;
    }
    // ---- transpose path ----
    __shared__ u16 tile[32][33];
    const float* src; u16* dst; int R, C;
    if (id < 3072)      {             src = Wqkv;  dst = WtQ;  R = 1024; C = 3072; }
    else if (id < 4096) { id -= 3072; src = Wattn; dst = WtA;  R = 1024; C = 1024; }
    else if (id < 6912) { id -= 4096; src = Wfc1;  dst = WtF1; R = 1024; C = 2816; }
    else if (id < 9728) { id -= 6912; src = Wfc2;  dst = WtF2; R = 1024; C = 2816; }
    else                { id -= 9728; src = Wmlp;  dst = WtM;  R = 2816; C = 1024; }
    const int nbx = C >> 5;
    const int bx = id % nbx, by = id / nbx;
    const int cx = bx * 32, ry = by * 32;
    #pragma unroll
    for (int i = 0; i < 32; i += 8)
        tile[ty + i][tx] = f2b(src[(size_t)(ry + ty + i) * C + cx + tx]);
    __syncthreads();
    #pragma unroll
    for (int i = 0; i < 32; i += 8)
        dst[(size_t)(cx + ty + i) * R + ry + tx] = tile[tx][ty + i];
}

// ---- rmsnorm (row = 1024): fp32 in, fp32 scale, bf16 out ----
__global__ __launch_bounds__(256) void rmsnorm_f32(const float* __restrict__ xin,
                                                   const float* __restrict__ scale,
                                                   u16* __restrict__ out) {
    const int row = blockIdx.x, tid = threadIdx.x;
    const float4 v = ((const float4*)(xin + (size_t)row * 1024))[tid];
    float ss = v.x * v.x + v.y * v.y + v.z * v.z + v.w * v.w;
    #pragma unroll
    for (int d = 32; d; d >>= 1) ss += __shfl_xor(ss, d);
    __shared__ float wsum[4];
    if ((tid & 63) == 0) wsum[tid >> 6] = ss;
    __syncthreads();
    const float r = rsqrtf((wsum[0] + wsum[1] + wsum[2] + wsum[3]) * (1.f / 1024.f) + 1e-5f);
    const float4 sc = ((const float4*)scale)[tid];
    uint2 o;
    o.x = cvt_pk_bf16(v.x * sc.x * r, v.y * sc.y * r);
    o.y = cvt_pk_bf16(v.z * sc.z * r, v.w * sc.w * r);
    ((uint2*)(out + (size_t)row * 1024))[tid] = o;
}

// ---- RoPE in place on q,k thirds of qkv (4096 x 3072 bf16) ----
// One thread per (row, i): trig computed ONCE, applied to 16 q-heads + 16 k-heads
// via coalesced u32 accesses (lanes 0..31 span i -> 128B contiguous per head).
__global__ __launch_bounds__(256) void rope_kernel(u16* __restrict__ qkv) {
    const int gid = blockIdx.x * 256 + threadIdx.x;  // 131072 = 4096 rows * 32 i
    const int i = gid & 31;
    const int row = gid >> 5;
    const int tpos = row & 2047;
    const float theta = expf(-(float)i * (9.210340371976184f / 32.0f));
    const float ang = (float)tpos * theta;
    const float c = cosf(ang), s = sinf(ang);
    uint32_t* p = (uint32_t*)qkv + (size_t)row * 1536 + i;
    #pragma unroll
    for (int h = 0; h < 16; ++h) {
        const uint32_t uq = p[h * 32];
        {
            const float xe = b2f((u16)(uq & 0xffff)), xo = b2f((u16)(uq >> 16));
            p[h * 32] = cvt_pk_bf16(xe * c - xo * s, xe * s + xo * c);
        }
        const uint32_t uk = p[512 + h * 32];
        {
            const float xe = b2f((u16)(uk & 0xffff)), xo = b2f((u16)(uk >> 16));
            p[512 + h * 32] = cvt_pk_bf16(xe * c - xo * s, xe * s + xo * c);
        }
    }
}

// ---- GEMM: A (M x K) bf16, Bt (N x K) bf16, 128x128 tile, 2x BK=32 halves per
// barrier pair (8 stage16 in flight, 32 MFMA per drain). Default block mapping.
// EPI 0: Cbf16; EPI 1: Cf32 = acc + Res_f32
template <int EPI>
__global__ __launch_bounds__(256) void gemm_bt(const u16* __restrict__ A,
                                               const u16* __restrict__ Bt,
                                               void* __restrict__ Cout,
                                               const void* __restrict__ Res,
                                               int N, int K) {
    __shared__ __attribute__((aligned(16))) u16 As[2][128 * 32];
    __shared__ __attribute__((aligned(16))) u16 Bs[2][128 * 32];
    const int tid = threadIdx.x;
    const int w = tid >> 6, lane = tid & 63;
    const int quad = lane >> 4, t = lane & 15;
    const int m0 = blockIdx.y * 128, n0 = blockIdx.x * 128;
    const int wm = (w >> 1) * 64, wn = (w & 1) * 64;

    const int srow = w * 16 + (lane >> 2);
    const int scol = (lane & 3) * 8;
    const u16* pA0 = A + (size_t)(m0 + srow) * K + scol;
    const u16* pA1 = pA0 + (size_t)64 * K;
    const u16* pB0 = Bt + (size_t)(n0 + srow) * K + scol;
    const u16* pB1 = pB0 + (size_t)64 * K;

    f32x4 acc[4][4];
    #pragma unroll
    for (int i = 0; i < 4; ++i)
        #pragma unroll
        for (int j = 0; j < 4; ++j) acc[i][j] = (f32x4){0.f, 0.f, 0.f, 0.f};

    for (int kb = 0; kb < K; kb += 64) {
        __syncthreads();                 // prior iteration's LDS reads complete
        stage16(pA0 + kb,      (char*)As[0] + w * 1024);
        stage16(pA1 + kb,      (char*)As[0] + 4096 + w * 1024);
        stage16(pB0 + kb,      (char*)Bs[0] + w * 1024);
        stage16(pB1 + kb,      (char*)Bs[0] + 4096 + w * 1024);
        stage16(pA0 + kb + 32, (char*)As[1] + w * 1024);
        stage16(pA1 + kb + 32, (char*)As[1] + 4096 + w * 1024);
        stage16(pB0 + kb + 32, (char*)Bs[1] + w * 1024);
        stage16(pB1 + kb + 32, (char*)Bs[1] + 4096 + w * 1024);
        __syncthreads();                 // vmcnt(0) drain: staging visible
        #pragma unroll
        for (int hf = 0; hf < 2; ++hf) {
            bf16x8 af[4], bfr[4];
            #pragma unroll
            for (int mi = 0; mi < 4; ++mi)
                af[mi] = *(const bf16x8*)((char*)As[hf] + (wm + mi * 16 + t) * 64 + quad * 16);
            #pragma unroll
            for (int ni = 0; ni < 4; ++ni)
                bfr[ni] = *(const bf16x8*)((char*)Bs[hf] + (wn + ni * 16 + t) * 64 + quad * 16);
            #pragma unroll
            for (int mi = 0; mi < 4; ++mi)
                #pragma unroll
                for (int ni = 0; ni < 4; ++ni)
                    acc[mi][ni] = __builtin_amdgcn_mfma_f32_16x16x32_bf16(af[mi], bfr[ni],
                                                                         acc[mi][ni], 0, 0, 0);
        }
    }
    #pragma unroll
    for (int mi = 0; mi < 4; ++mi) {
        const int row0 = m0 + wm + mi * 16 + quad * 4;
        #pragma unroll
        for (int ni = 0; ni < 4; ++ni) {
            const int col = n0 + wn + ni * 16 + t;
            #pragma unroll
            for (int r = 0; r < 4; r += 2) {
                const size_t idx0 = (size_t)(row0 + r) * N + col;
                const size_t idx1 = (size_t)(row0 + r + 1) * N + col;
                if (EPI == 0) {
                    const uint32_t pk2 = cvt_pk_bf16(acc[mi][ni][r], acc[mi][ni][r + 1]);
                    ((u16*)Cout)[idx0] = (u16)pk2;
                    ((u16*)Cout)[idx1] = (u16)(pk2 >> 16);
                } else {
                    ((float*)Cout)[idx0] = acc[mi][ni][r]     + ((const float*)Res)[idx0];
                    ((float*)Cout)[idx1] = acc[mi][ni][r + 1] + ((const float*)Res)[idx1];
                }
            }
        }
    }
}

// ---- GEMM variant: 128x64 tile for N=1024 shapes (512 blocks -> 2 blocks/CU) ----
template <int EPI>
__global__ __launch_bounds__(256) void gemm_bt64(const u16* __restrict__ A,
                                                 const u16* __restrict__ Bt,
                                                 void* __restrict__ Cout,
                                                 const float* __restrict__ Res,
                                                 int N, int K) {
    __shared__ __attribute__((aligned(16))) u16 As[2][128 * 32];  // 16 KB
    __shared__ __attribute__((aligned(16))) u16 Bs[2][64 * 32];   // 8 KB
    const int tid = threadIdx.x;
    const int w = tid >> 6, lane = tid & 63;
    const int quad = lane >> 4, t = lane & 15;
    const int m0 = blockIdx.y * 128, n0 = blockIdx.x * 64;
    const int wm = (w >> 1) * 64, wn = (w & 1) * 32;

    const int srow = w * 16 + (lane >> 2);
    const int scol = (lane & 3) * 8;
    const u16* pA0 = A + (size_t)(m0 + srow) * K + scol;
    const u16* pA1 = pA0 + (size_t)64 * K;
    const u16* pB0 = Bt + (size_t)(n0 + srow) * K + scol;

    f32x4 acc[4][2];
    #pragma unroll
    for (int i = 0; i < 4; ++i)
        #pragma unroll
        for (int j = 0; j < 2; ++j) acc[i][j] = (f32x4){0.f, 0.f, 0.f, 0.f};

    for (int kb = 0; kb < K; kb += 64) {
        __syncthreads();
        stage16(pA0 + kb,      (char*)As[0] + w * 1024);
        stage16(pA1 + kb,      (char*)As[0] + 4096 + w * 1024);
        stage16(pB0 + kb,      (char*)Bs[0] + w * 1024);
        stage16(pA0 + kb + 32, (char*)As[1] + w * 1024);
        stage16(pA1 + kb + 32, (char*)As[1] + 4096 + w * 1024);
        stage16(pB0 + kb + 32, (char*)Bs[1] + w * 1024);
        __syncthreads();
        #pragma unroll
        for (int hf = 0; hf < 2; ++hf) {
            bf16x8 af[4], bfr[2];
            #pragma unroll
            for (int mi = 0; mi < 4; ++mi)
                af[mi] = *(const bf16x8*)((char*)As[hf] + (wm + mi * 16 + t) * 64 + quad * 16);
            #pragma unroll
            for (int ni = 0; ni < 2; ++ni)
                bfr[ni] = *(const bf16x8*)((char*)Bs[hf] + (wn + ni * 16 + t) * 64 + quad * 16);
            #pragma unroll
            for (int mi = 0; mi < 4; ++mi)
                #pragma unroll
                for (int ni = 0; ni < 2; ++ni)
                    acc[mi][ni] = __builtin_amdgcn_mfma_f32_16x16x32_bf16(af[mi], bfr[ni],
                                                                         acc[mi][ni], 0, 0, 0);
        }
    }
    #pragma unroll
    for (int mi = 0; mi < 4; ++mi) {
        const int row0 = m0 + wm + mi * 16 + quad * 4;
        #pragma unroll
        for (int ni = 0; ni < 2; ++ni) {
            const int col = n0 + wn + ni * 16 + t;
            #pragma unroll
            for (int r = 0; r < 4; ++r) {
                const size_t idx = (size_t)(row0 + r) * N + col;
                const float v = acc[mi][ni][r];
                if (EPI == 0) ((u16*)Cout)[idx]   = f2b(v);
                else          ((float*)Cout)[idx] = v + Res[idx];
            }
        }
    }
}

// ---- FUSED fc1+fc2 GEMM: A (M x K), B1t/B2t (N x K); C = silu(A@W1) * (A@W2).
// A staged ONCE for both B operands; silu-mul in-register; one dispatch.
__global__ __launch_bounds__(256) void gemm_fc(const u16* __restrict__ A,
                                               const u16* __restrict__ B1t,
                                               const u16* __restrict__ B2t,
                                               u16* __restrict__ Cout,
                                               int N, int K) {
    __shared__ __attribute__((aligned(16))) u16 As[2][128 * 32];   // 16 KB
    __shared__ __attribute__((aligned(16))) u16 B1s[2][64 * 32];   // 8 KB
    __shared__ __attribute__((aligned(16))) u16 B2s[2][64 * 32];   // 8 KB
    const int tid = threadIdx.x;
    const int w = tid >> 6, lane = tid & 63;
    const int quad = lane >> 4, t = lane & 15;
    const int m0 = blockIdx.y * 128, n0 = blockIdx.x * 64;
    const int wm = (w >> 1) * 64, wn = (w & 1) * 32;

    const int srow = w * 16 + (lane >> 2);
    const int scol = (lane & 3) * 8;
    const u16* pA0 = A + (size_t)(m0 + srow) * K + scol;
    const u16* pA1 = pA0 + (size_t)64 * K;
    const u16* pB1 = B1t + (size_t)(n0 + srow) * K + scol;
    const u16* pB2 = B2t + (size_t)(n0 + srow) * K + scol;

    f32x4 acc1[4][2], acc2[4][2];
    #pragma unroll
    for (int i = 0; i < 4; ++i)
        #pragma unroll
        for (int j = 0; j < 2; ++j) {
            acc1[i][j] = (f32x4){0.f, 0.f, 0.f, 0.f};
            acc2[i][j] = (f32x4){0.f, 0.f, 0.f, 0.f};
        }

    for (int kb = 0; kb < K; kb += 64) {
        __syncthreads();
        stage16(pA0 + kb,      (char*)As[0] + w * 1024);
        stage16(pA1 + kb,      (char*)As[0] + 4096 + w * 1024);
        stage16(pB1 + kb,      (char*)B1s[0] + w * 1024);
        stage16(pB2 + kb,      (char*)B2s[0] + w * 1024);
        stage16(pA0 + kb + 32, (char*)As[1] + w * 1024);
        stage16(pA1 + kb + 32, (char*)As[1] + 4096 + w * 1024);
        stage16(pB1 + kb + 32, (char*)B1s[1] + w * 1024);
        stage16(pB2 + kb + 32, (char*)B2s[1] + w * 1024);
        __syncthreads();
        #pragma unroll
        for (int hf = 0; hf < 2; ++hf) {
            bf16x8 af[4], b1r[2], b2r[2];
            #pragma unroll
            for (int mi = 0; mi < 4; ++mi)
                af[mi] = *(const bf16x8*)((char*)As[hf] + (wm + mi * 16 + t) * 64 + quad * 16);
            #pragma unroll
            for (int ni = 0; ni < 2; ++ni) {
                b1r[ni] = *(const bf16x8*)((char*)B1s[hf] + (wn + ni * 16 + t) * 64 + quad * 16);
                b2r[ni] = *(const bf16x8*)((char*)B2s[hf] + (wn + ni * 16 + t) * 64 + quad * 16);
            }
            #pragma unroll
            for (int mi = 0; mi < 4; ++mi)
                #pragma unroll
                for (int ni = 0; ni < 2; ++ni) {
                    acc1[mi][ni] = __builtin_amdgcn_mfma_f32_16x16x32_bf16(af[mi], b1r[ni],
                                                                          acc1[mi][ni], 0, 0, 0);
                    acc2[mi][ni] = __builtin_amdgcn_mfma_f32_16x16x32_bf16(af[mi], b2r[ni],
                                                                          acc2[mi][ni], 0, 0, 0);
                }
        }
    }
    #pragma unroll
    for (int mi = 0; mi < 4; ++mi) {
        const int row0 = m0 + wm + mi * 16 + quad * 4;
        #pragma unroll
        for (int ni = 0; ni < 2; ++ni) {
            const int col = n0 + wn + ni * 16 + t;
            float mv[4];
            #pragma unroll
            for (int r = 0; r < 4; ++r) {
                const float a = acc1[mi][ni][r];
                mv[r] = (a / (1.f + __expf(-a))) * acc2[mi][ni][r];
            }
            #pragma unroll
            for (int r = 0; r < 4; r += 2) {
                const uint32_t pk2 = cvt_pk_bf16(mv[r], mv[r + 1]);
                Cout[(size_t)(row0 + r) * N + col]     = (u16)pk2;
                Cout[(size_t)(row0 + r + 1) * N + col] = (u16)(pk2 >> 16);
            }
        }
    }
}

// ---- flash attention: qkv (4096 x 3072 bf16, roped), y (4096 x 1024 bf16) ----
// BEST-MEASURED FORM (R10/R11: 75.0 us): KVBLK=64, pair-balanced (33 uniform
// K-tiles/block), XCD-GROUPED mapping (FETCH 12.4 MB), DPP softmax, diagonal-only
// mask, folded Q-scale, Vts XOR-swizzled, scalar f2b in the softmax chain.
// (R12's KVBLK=128 regressed -7.7us: register pressure -> spill traffic.)
__global__ __launch_bounds__(256) void attn_kernel(const u16* __restrict__ qkv,
                                                   const int* __restrict__ ymask,
                                                   u16* __restrict__ y) {
    const int gid = blockIdx.x;              // 0..511
    const int xcd = gid & 7;
    const int j2 = gid >> 3;                 // 0..63
    const int slot = j2 >> 4;                // 0..3
    const int pairk = j2 & 15;               // 0..15
    const int group = slot * 8 + xcd;        // 0..31
    const int h = group & 15, b = group >> 4;
    const int tid = threadIdx.x;
    const int w = tid >> 6, lane = tid & 63;
    const int quad = lane >> 4, t = lane & 15;

    __shared__ __attribute__((aligned(16))) u16 Ks[64 * 72];    // [key][d], 144B rows
    __shared__ __attribute__((aligned(16))) u16 Vts[64 * 72];   // [d][key], swizzled
    __shared__ __attribute__((aligned(16))) u16 Ps[4][16 * 72]; // per-wave P [m][key]
    __shared__ int ymL[64];
    if (pairk == 0 && tid < 64) ymL[tid] = ymask[b * 64 + tid];

    // staging assignment: thread -> (key = tid>>3 and +32, dg = tid&7)
    const int skey = tid >> 3, sdg = tid & 7;
    const u16* pK = qkv + (size_t)(b * 2048 + skey) * 3072 + h * 64 + sdg * 8 + 1024;
    const int sblk0 = (skey >> 3) ^ sdg;          // Vts block for keys 0..31 set
    const int sblk1 = (4 + (skey >> 3)) ^ sdg;    // keys 32..63 set

    for (int seg = 0; seg < 2; ++seg) {
        const int qt = seg ? pairk : 31 - pairk;  // long segment first
        const int q0 = qt * 64;

        bf16x8 aQ[2];
        {
            const u16* qp = qkv + (size_t)(b * 2048 + q0 + w * 16 + t) * 3072 + h * 64 + quad * 8;
            aQ[0] = *(const bf16x8*)qp;
            aQ[1] = *(const bf16x8*)(qp + 32);
            #pragma unroll
            for (int i = 0; i < 8; ++i) {   // fold 1/sqrt(64): *2^-3 exact in bf16
                aQ[0][i] = (short)f2b(b2f((u16)aQ[0][i]) * 0.125f);
                aQ[1][i] = (short)f2b(b2f((u16)aQ[1][i]) * 0.125f);
            }
        }

        f32x4 accO[4] = {(f32x4){0,0,0,0},(f32x4){0,0,0,0},(f32x4){0,0,0,0},(f32x4){0,0,0,0}};
        float mOld[4] = {-INFINITY, -INFINITY, -INFINITY, -INFINITY};
        float lSum[4] = {0.f, 0.f, 0.f, 0.f};

        for (int kb = 0; kb <= qt; ++kb) {
            // global loads issued before the barrier (latency overlaps drain)
            const u16* pk = pK + (size_t)kb * 196608;        // kb*64*3072
            const uint4 kv0 = *(const uint4*)pk;
            const uint4 vv0 = *(const uint4*)(pk + 1024);
            const uint4 kv1 = *(const uint4*)(pk + 98304);   // +32*3072
            const uint4 vv1 = *(const uint4*)(pk + 99328);
            __syncthreads();                 // prior iteration's LDS reads done
            *(uint4*)((char*)Ks + skey * 144 + sdg * 16) = kv0;
            *(uint4*)((char*)Ks + (skey + 32) * 144 + sdg * 16) = kv1;
            {
                const u16* vp0 = (const u16*)&vv0;
                const u16* vp1 = (const u16*)&vv1;
                #pragma unroll
                for (int jj = 0; jj < 8; ++jj) {
                    const int row = sdg * 8 + jj;
                    Vts[row * 72 + sblk0 * 8 + (skey & 7)] = vp0[jj];
                    Vts[row * 72 + sblk1 * 8 + (skey & 7)] = vp1[jj];
                }
            }
            __syncthreads();

            float s[4][4];
            __builtin_amdgcn_s_setprio(1);
            #pragma unroll
            for (int ni = 0; ni < 4; ++ni) {
                bf16x8 bK0 = *(const bf16x8*)((char*)Ks + (ni * 16 + t) * 144 + quad * 16);
                bf16x8 bK1 = *(const bf16x8*)((char*)Ks + (ni * 16 + t) * 144 + 64 + quad * 16);
                f32x4 sa = (f32x4){0.f, 0.f, 0.f, 0.f};
                sa = __builtin_amdgcn_mfma_f32_16x16x32_bf16(aQ[0], bK0, sa, 0, 0, 0);
                sa = __builtin_amdgcn_mfma_f32_16x16x32_bf16(aQ[1], bK1, sa, 0, 0, 0);
                #pragma unroll
                for (int r = 0; r < 4; ++r) s[ni][r] = sa[r];
            }
            __builtin_amdgcn_s_setprio(0);

            // mask only on the diagonal tile; ym text-mask only in the qt==0 tile.
            if (kb == qt) {
                const int irow = q0 + w * 16 + quad * 4;
                #pragma unroll
                for (int ni = 0; ni < 4; ++ni)
                    #pragma unroll
                    for (int r = 0; r < 4; ++r) {
                        const int i = irow + r, j = kb * 64 + ni * 16 + t;
                        const bool ok = (j <= i) || (qt == 0 && ymL[i & 63] && ymL[j & 63]);
                        if (!ok) s[ni][r] = -INFINITY;
                    }
            }

            float alpha[4];
            bool upd = false;
            #pragma unroll
            for (int r = 0; r < 4; ++r) {
                float mt = fmaxf(fmaxf(s[0][r], s[1][r]), fmaxf(s[2][r], s[3][r]));
                mt = rowmax16(mt);                       // DPP, VALU-rate
                const float mNew = fmaxf(mOld[r], mt);
                upd = upd || (mNew > mOld[r]);
                alpha[r] = __expf(mOld[r] - mNew);
                #pragma unroll
                for (int ni = 0; ni < 4; ++ni) s[ni][r] = __expf(s[ni][r] - mNew);
                mOld[r] = mNew;
            }

            // P (C-layout) -> per-wave LDS, issued early; ds_write latency hides
            // under the DPP sum-reduces below. Same-wave, no barrier needed.
            u16* Pw = Ps[w];
            #pragma unroll
            for (int ni = 0; ni < 4; ++ni)
                #pragma unroll
                for (int r = 0; r < 4; ++r)
                    Pw[(quad * 4 + r) * 72 + ni * 16 + t] = f2b(s[ni][r]);

            #pragma unroll
            for (int r = 0; r < 4; ++r) {
                float rs = (s[0][r] + s[1][r]) + (s[2][r] + s[3][r]);
                rs = rowsum16(rs);                       // DPP, VALU-rate
                lSum[r] = lSum[r] * alpha[r] + rs;
            }
            if (__any(upd)) {               // skip O-rescale when no row's max moved
                #pragma unroll
                for (int dt = 0; dt < 4; ++dt)
                    #pragma unroll
                    for (int r = 0; r < 4; ++r) accO[dt][r] *= alpha[r];
            }

            bf16x8 aP0 = *(const bf16x8*)((char*)Pw + t * 144 + quad * 16);
            bf16x8 aP1 = *(const bf16x8*)((char*)Pw + t * 144 + 64 + quad * 16);
            __builtin_amdgcn_s_setprio(1);
            #pragma unroll
            for (int dt = 0; dt < 4; ++dt) {
                const int row = dt * 16 + t, rb = row >> 3;
                bf16x8 bV0 = *(const bf16x8*)((char*)Vts + row * 144 + ((quad ^ rb) << 4));
                bf16x8 bV1 = *(const bf16x8*)((char*)Vts + row * 144 + (((4 + quad) ^ rb) << 4));
                accO[dt] = __builtin_amdgcn_mfma_f32_16x16x32_bf16(aP0, bV0, accO[dt], 0, 0, 0);
                accO[dt] = __builtin_amdgcn_mfma_f32_16x16x32_bf16(aP1, bV1, accO[dt], 0, 0, 0);
            }
            __builtin_amdgcn_s_setprio(0);
        }
        const int orow = q0 + w * 16 + quad * 4;
        #pragma unroll
        for (int dt = 0; dt < 4; ++dt)
            #pragma unroll
            for (int r = 0; r < 4; ++r) {
                const size_t idx = (size_t)(b * 2048 + orow + r) * 1024 + h * 64 + dt * 16 + t;
                y[idx] = f2b(accO[dt][r] / lSum[r]);
            }
    }
}

extern "C" void kernel_launch(void* const* d_in, const int* in_sizes, int n_in,
                              void* d_out, int out_size, void* d_ws, size_t ws_size,
                              hipStream_t stream) {
    const float* x     = (const float*)d_in[0];
    const int*   ym    = (const int*)d_in[1];
    const float* Wqkv  = (const float*)d_in[2];
    const float* Wattn = (const float*)d_in[3];
    const float* s1    = (const float*)d_in[4];
    const float* s2    = (const float*)d_in[5];
    const float* Wfc1  = (const float*)d_in[6];
    const float* Wfc2  = (const float*)d_in[7];
    const float* Wmlp  = (const float*)d_in[8];

    char* ws = (char*)d_ws;
    u16*    h    = (u16*)(ws + 0);          // 8 MB bf16; reused as attention output
    u16*    qkv  = (u16*)(ws + 8388608);    // 24 MB bf16; later reused as fc1/m
    u16*    fc1  = qkv;
    float*  xr   = (float*)(ws + 33554432); // 16 MB fp32 residual
    u16*    WtA  = (u16*)(ws + 50331648);   // 2 MB
    u16*    WtF1 = (u16*)(ws + 52428800);   // 5.5 MB
    u16*    WtF2 = (u16*)(ws + 58195968);   // 5.5 MB
    u16*    WtM  = (u16*)(ws + 63963136);   // 5.5 MB
    u16*    WtQ  = (u16*)(ws + 73400320);   // 6 MB
    const dim3 tb(32, 8);

    prep_kernel<<<16640, tb, 0, stream>>>(Wqkv, Wattn, Wfc1, Wfc2, Wmlp,
                                          WtQ, WtA, WtF1, WtF2, WtM, x, s1, h);
    gemm_bt<0><<<dim3(24, 32), 256, 0, stream>>>(h, WtQ, qkv, nullptr, 3072, 1024);
    rope_kernel<<<512, 256, 0, stream>>>(qkv);
    attn_kernel<<<512, 256, 0, stream>>>(qkv, ym, h);   // h dead -> y
    gemm_bt64<1><<<dim3(16, 32), 256, 0, stream>>>(h, WtA, xr, x, 1024, 1024);
    rmsnorm_f32<<<4096, 256, 0, stream>>>(xr, s2, h);
    gemm_fc<<<dim3(44, 32), 256, 0, stream>>>(h, WtF1, WtF2, fc1, 2816, 1024);
    gemm_bt64<1><<<dim3(16, 32), 256, 0, stream>>>(fc1, WtM, (float*)d_out, xr, 1024, 2816);
}

// Round 14
// 347.796 us; speedup vs baseline: 1.0636x; 1.0001x over previous
//
#include <hip/hip_runtime.h>
#include <stdint.h>

typedef unsigned short u16;
typedef __attribute__((ext_vector_type(8))) short bf16x8;
typedef __attribute__((ext_vector_type(4))) float f32x4;

__device__ __forceinline__ float b2f(u16 u) {
    union { float f; uint32_t u; } v; v.u = ((uint32_t)u) << 16; return v.f;
}
__device__ __forceinline__ u16 f2b(float f) {
    union { float f; uint32_t u; } v; v.f = f;
    uint32_t r = v.u + 0x7FFFu + ((v.u >> 16) & 1u);
    return (u16)(r >> 16);
}
// HW packed f32->bf16 (RNE): 2 values in 1 instruction (no builtin on gfx950)
__device__ __forceinline__ uint32_t cvt_pk_bf16(float lo, float hi) {
    uint32_t r;
    asm("v_cvt_pk_bf16_f32 %0, %1, %2" : "=v"(r) : "v"(lo), "v"(hi));
    return r;
}

// DPP cross-lane move within 16-lane rows (row_ror:N = 0x120+N). Full-rate VALU.
template <int CTRL>
__device__ __forceinline__ float dppf(float x) {
    union { float f; int i; } u; u.f = x;
    u.i = __builtin_amdgcn_update_dpp(0, u.i, CTRL, 0xF, 0xF, false);
    return u.f;
}
// all-lanes max/sum over each 16-lane DPP row via rotate-reduce
__device__ __forceinline__ float rowmax16(float v) {
    v = fmaxf(v, dppf<0x121>(v));   // ror 1
    v = fmaxf(v, dppf<0x122>(v));   // ror 2
    v = fmaxf(v, dppf<0x124>(v));   // ror 4
    v = fmaxf(v, dppf<0x128>(v));   // ror 8
    return v;
}
__device__ __forceinline__ float rowsum16(float v) {
    v += dppf<0x121>(v);
    v += dppf<0x122>(v);
    v += dppf<0x124>(v);
    v += dppf<0x128>(v);
    return v;
}

// async global->LDS, 16B/lane. LDS dest must be wave-uniform; HW adds lane*16.
__device__ __forceinline__ void stage16(const void* g, void* l) {
    __builtin_amdgcn_global_load_lds(
        (const __attribute__((address_space(1))) uint32_t*)(uintptr_t)g,
        (__attribute__((address_space(3))) uint32_t*)(uint32_t)(uintptr_t)l,
        16, 0, 0);
}

// ---- fused preprocessing: 5 weight transposes + rmsnorm1, ONE launch ----
// blocks 0..12543: transpose tiles; blocks 12544..16639: rmsnorm rows.
__global__ __launch_bounds__(256) void prep_kernel(const float* __restrict__ Wqkv,
                                                   const float* __restrict__ Wattn,
                                                   const float* __restrict__ Wfc1,
                                                   const float* __restrict__ Wfc2,
                                                   const float* __restrict__ Wmlp,
                                                   u16* WtQ, u16* WtA, u16* WtF1,
                                                   u16* WtF2, u16* WtM,
                                                   const float* __restrict__ xin,
                                                   const float* __restrict__ scale,
                                                   u16* __restrict__ xout) {
    const int tx = threadIdx.x, ty = threadIdx.y; // 32 x 8
    int id = blockIdx.x;
    if (id >= 12544) {
        // ---- rmsnorm path ----
        const int row = id - 12544, tid = ty * 32 + tx;
        const float4 v = ((const float4*)(xin + (size_t)row * 1024))[tid];
        float ss = v.x * v.x + v.y * v.y + v.z * v.z + v.w * v.w;
        #pragma unroll
        for (int d = 32; d; d >>= 1) ss += __shfl_xor(ss, d);
        __shared__ float wsum[4];
        if ((tid & 63) == 0) wsum[tid >> 6] = ss;
        __syncthreads();
        const float r = rsqrtf((wsum[0] + wsum[1] + wsum[2] + wsum[3]) * (1.f / 1024.f) + 1e-5f);
        const float4 sc = ((const float4*)scale)[tid];
        uint2 o;
        o.x = cvt_pk_bf16(v.x * sc.x * r, v.y * sc.y * r);
        o.y = cvt_pk_bf16(v.z * sc.z * r, v.w * sc.w * r);
        ((uint2*)(xout + (size_t)row * 1024))[tid] = o;
        return;
    }
    // ---- transpose path ----
    __shared__ u16 tile[32][33];
    const float* src; u16* dst; int R, C;
    if (id < 3072)      {             src = Wqkv;  dst = WtQ;  R = 1024; C = 3072; }
    else if (id < 4096) { id -= 3072; src = Wattn; dst = WtA;  R = 1024; C = 1024; }
    else if (id < 6912) { id -= 4096; src = Wfc1;  dst = WtF1; R = 1024; C = 2816; }
    else if (id < 9728) { id -= 6912; src = Wfc2;  dst = WtF2; R = 1024; C = 2816; }
    else                { id -= 9728; src = Wmlp;  dst = WtM;  R = 2816; C = 1024; }
    const int nbx = C >> 5;
    const int bx = id % nbx, by = id / nbx;
    const int cx = bx * 32, ry = by * 32;
    #pragma unroll
    for (int i = 0; i < 32; i += 8)
        tile[ty + i][tx] = f2b(src[(size_t)(ry + ty + i) * C + cx + tx]);
    __syncthreads();
    #pragma unroll
    for (int i = 0; i < 32; i += 8)
        dst[(size_t)(cx + ty + i) * R + ry + tx] = tile[tx][ty + i];
}

// ---- rmsnorm (row = 1024): fp32 in, fp32 scale, bf16 out ----
__global__ __launch_bounds__(256) void rmsnorm_f32(const float* __restrict__ xin,
                                                   const float* __restrict__ scale,
                                                   u16* __restrict__ out) {
    const int row = blockIdx.x, tid = threadIdx.x;
    const float4 v = ((const float4*)(xin + (size_t)row * 1024))[tid];
    float ss = v.x * v.x + v.y * v.y + v.z * v.z + v.w * v.w;
    #pragma unroll
    for (int d = 32; d; d >>= 1) ss += __shfl_xor(ss, d);
    __shared__ float wsum[4];
    if ((tid & 63) == 0) wsum[tid >> 6] = ss;
    __syncthreads();
    const float r = rsqrtf((wsum[0] + wsum[1] + wsum[2] + wsum[3]) * (1.f / 1024.f) + 1e-5f);
    const float4 sc = ((const float4*)scale)[tid];
    uint2 o;
    o.x = cvt_pk_bf16(v.x * sc.x * r, v.y * sc.y * r);
    o.y = cvt_pk_bf16(v.z * sc.z * r, v.w * sc.w * r);
    ((uint2*)(out + (size_t)row * 1024))[tid] = o;
}

// ---- RoPE in place on q,k thirds of qkv (4096 x 3072 bf16) ----
// One thread per (row, i): trig computed ONCE, applied to 16 q-heads + 16 k-heads
// via coalesced u32 accesses (lanes 0..31 span i -> 128B contiguous per head).
__global__ __launch_bounds__(256) void rope_kernel(u16* __restrict__ qkv) {
    const int gid = blockIdx.x * 256 + threadIdx.x;  // 131072 = 4096 rows * 32 i
    const int i = gid & 31;
    const int row = gid >> 5;
    const int tpos = row & 2047;
    const float theta = expf(-(float)i * (9.210340371976184f / 32.0f));
    const float ang = (float)tpos * theta;
    const float c = cosf(ang), s = sinf(ang);
    uint32_t* p = (uint32_t*)qkv + (size_t)row * 1536 + i;
    #pragma unroll
    for (int h = 0; h < 16; ++h) {
        const uint32_t uq = p[h * 32];
        {
            const float xe = b2f((u16)(uq & 0xffff)), xo = b2f((u16)(uq >> 16));
            p[h * 32] = cvt_pk_bf16(xe * c - xo * s, xe * s + xo * c);
        }
        const uint32_t uk = p[512 + h * 32];
        {
            const float xe = b2f((u16)(uk & 0xffff)), xo = b2f((u16)(uk >> 16));
            p[512 + h * 32] = cvt_pk_bf16(xe * c - xo * s, xe * s + xo * c);
        }
    }
}

// ---- GEMM: A (M x K) bf16, Bt (N x K) bf16, 128x128 tile, 2x BK=32 halves per
// barrier pair (8 stage16 in flight, 32 MFMA per drain). Default block mapping.
// EPI 0: Cbf16; EPI 1: Cf32 = acc + Res_f32
template <int EPI>
__global__ __launch_bounds__(256) void gemm_bt(const u16* __restrict__ A,
                                               const u16* __restrict__ Bt,
                                               void* __restrict__ Cout,
                                               const void* __restrict__ Res,
                                               int N, int K) {
    __shared__ __attribute__((aligned(16))) u16 As[2][128 * 32];
    __shared__ __attribute__((aligned(16))) u16 Bs[2][128 * 32];
    const int tid = threadIdx.x;
    const int w = tid >> 6, lane = tid & 63;
    const int quad = lane >> 4, t = lane & 15;
    const int m0 = blockIdx.y * 128, n0 = blockIdx.x * 128;
    const int wm = (w >> 1) * 64, wn = (w & 1) * 64;

    const int srow = w * 16 + (lane >> 2);
    const int scol = (lane & 3) * 8;
    const u16* pA0 = A + (size_t)(m0 + srow) * K + scol;
    const u16* pA1 = pA0 + (size_t)64 * K;
    const u16* pB0 = Bt + (size_t)(n0 + srow) * K + scol;
    const u16* pB1 = pB0 + (size_t)64 * K;

    f32x4 acc[4][4];
    #pragma unroll
    for (int i = 0; i < 4; ++i)
        #pragma unroll
        for (int j = 0; j < 4; ++j) acc[i][j] = (f32x4){0.f, 0.f, 0.f, 0.f};

    for (int kb = 0; kb < K; kb += 64) {
        __syncthreads();                 // prior iteration's LDS reads complete
        stage16(pA0 + kb,      (char*)As[0] + w * 1024);
        stage16(pA1 + kb,      (char*)As[0] + 4096 + w * 1024);
        stage16(pB0 + kb,      (char*)Bs[0] + w * 1024);
        stage16(pB1 + kb,      (char*)Bs[0] + 4096 + w * 1024);
        stage16(pA0 + kb + 32, (char*)As[1] + w * 1024);
        stage16(pA1 + kb + 32, (char*)As[1] + 4096 + w * 1024);
        stage16(pB0 + kb + 32, (char*)Bs[1] + w * 1024);
        stage16(pB1 + kb + 32, (char*)Bs[1] + 4096 + w * 1024);
        __syncthreads();                 // vmcnt(0) drain: staging visible
        #pragma unroll
        for (int hf = 0; hf < 2; ++hf) {
            bf16x8 af[4], bfr[4];
            #pragma unroll
            for (int mi = 0; mi < 4; ++mi)
                af[mi] = *(const bf16x8*)((char*)As[hf] + (wm + mi * 16 + t) * 64 + quad * 16);
            #pragma unroll
            for (int ni = 0; ni < 4; ++ni)
                bfr[ni] = *(const bf16x8*)((char*)Bs[hf] + (wn + ni * 16 + t) * 64 + quad * 16);
            #pragma unroll
            for (int mi = 0; mi < 4; ++mi)
                #pragma unroll
                for (int ni = 0; ni < 4; ++ni)
                    acc[mi][ni] = __builtin_amdgcn_mfma_f32_16x16x32_bf16(af[mi], bfr[ni],
                                                                         acc[mi][ni], 0, 0, 0);
        }
    }
    #pragma unroll
    for (int mi = 0; mi < 4; ++mi) {
        const int row0 = m0 + wm + mi * 16 + quad * 4;
        #pragma unroll
        for (int ni = 0; ni < 4; ++ni) {
            const int col = n0 + wn + ni * 16 + t;
            #pragma unroll
            for (int r = 0; r < 4; r += 2) {
                const size_t idx0 = (size_t)(row0 + r) * N + col;
                const size_t idx1 = (size_t)(row0 + r + 1) * N + col;
                if (EPI == 0) {
                    const uint32_t pk2 = cvt_pk_bf16(acc[mi][ni][r], acc[mi][ni][r + 1]);
                    ((u16*)Cout)[idx0] = (u16)pk2;
                    ((u16*)Cout)[idx1] = (u16)(pk2 >> 16);
                } else {
                    ((float*)Cout)[idx0] = acc[mi][ni][r]     + ((const float*)Res)[idx0];
                    ((float*)Cout)[idx1] = acc[mi][ni][r + 1] + ((const float*)Res)[idx1];
                }
            }
        }
    }
}

// ---- GEMM variant: 128x64 tile for N=1024 shapes (512 blocks -> 2 blocks/CU) ----
template <int EPI>
__global__ __launch_bounds__(256) void gemm_bt64(const u16* __restrict__ A,
                                                 const u16* __restrict__ Bt,
                                                 void* __restrict__ Cout,
                                                 const float* __restrict__ Res,
                                                 int N, int K) {
    __shared__ __attribute__((aligned(16))) u16 As[2][128 * 32];  // 16 KB
    __shared__ __attribute__((aligned(16))) u16 Bs[2][64 * 32];   // 8 KB
    const int tid = threadIdx.x;
    const int w = tid >> 6, lane = tid & 63;
    const int quad = lane >> 4, t = lane & 15;
    const int m0 = blockIdx.y * 128, n0 = blockIdx.x * 64;
    const int wm = (w >> 1) * 64, wn = (w & 1) * 32;

    const int srow = w * 16 + (lane >> 2);
    const int scol = (lane & 3) * 8;
    const u16* pA0 = A + (size_t)(m0 + srow) * K + scol;
    const u16* pA1 = pA0 + (size_t)64 * K;
    const u16* pB0 = Bt + (size_t)(n0 + srow) * K + scol;

    f32x4 acc[4][2];
    #pragma unroll
    for (int i = 0; i < 4; ++i)
        #pragma unroll
        for (int j = 0; j < 2; ++j) acc[i][j] = (f32x4){0.f, 0.f, 0.f, 0.f};

    for (int kb = 0; kb < K; kb += 64) {
        __syncthreads();
        stage16(pA0 + kb,      (char*)As[0] + w * 1024);
        stage16(pA1 + kb,      (char*)As[0] + 4096 + w * 1024);
        stage16(pB0 + kb,      (char*)Bs[0] + w * 1024);
        stage16(pA0 + kb + 32, (char*)As[1] + w * 1024);
        stage16(pA1 + kb + 32, (char*)As[1] + 4096 + w * 1024);
        stage16(pB0 + kb + 32, (char*)Bs[1] + w * 1024);
        __syncthreads();
        #pragma unroll
        for (int hf = 0; hf < 2; ++hf) {
            bf16x8 af[4], bfr[2];
            #pragma unroll
            for (int mi = 0; mi < 4; ++mi)
                af[mi] = *(const bf16x8*)((char*)As[hf] + (wm + mi * 16 + t) * 64 + quad * 16);
            #pragma unroll
            for (int ni = 0; ni < 2; ++ni)
                bfr[ni] = *(const bf16x8*)((char*)Bs[hf] + (wn + ni * 16 + t) * 64 + quad * 16);
            #pragma unroll
            for (int mi = 0; mi < 4; ++mi)
                #pragma unroll
                for (int ni = 0; ni < 2; ++ni)
                    acc[mi][ni] = __builtin_amdgcn_mfma_f32_16x16x32_bf16(af[mi], bfr[ni],
                                                                         acc[mi][ni], 0, 0, 0);
        }
    }
    #pragma unroll
    for (int mi = 0; mi < 4; ++mi) {
        const int row0 = m0 + wm + mi * 16 + quad * 4;
        #pragma unroll
        for (int ni = 0; ni < 2; ++ni) {
            const int col = n0 + wn + ni * 16 + t;
            #pragma unroll
            for (int r = 0; r < 4; ++r) {
                const size_t idx = (size_t)(row0 + r) * N + col;
                const float v = acc[mi][ni][r];
                if (EPI == 0) ((u16*)Cout)[idx]   = f2b(v);
                else          ((float*)Cout)[idx] = v + Res[idx];
            }
        }
    }
}

// ---- FUSED fc1+fc2 GEMM: A (M x K), B1t/B2t (N x K); C = silu(A@W1) * (A@W2).
// A staged ONCE for both B operands; silu-mul in-register; one dispatch.
__global__ __launch_bounds__(256) void gemm_fc(const u16* __restrict__ A,
                                               const u16* __restrict__ B1t,
                                               const u16* __restrict__ B2t,
                                               u16* __restrict__ Cout,
                                               int N, int K) {
    __shared__ __attribute__((aligned(16))) u16 As[2][128 * 32];   // 16 KB
    __shared__ __attribute__((aligned(16))) u16 B1s[2][64 * 32];   // 8 KB
    __shared__ __attribute__((aligned(16))) u16 B2s[2][64 * 32];   // 8 KB
    const int tid = threadIdx.x;
    const int w = tid >> 6, lane = tid & 63;
    const int quad = lane >> 4, t = lane & 15;
    const int m0 = blockIdx.y * 128, n0 = blockIdx.x * 64;
    const int wm = (w >> 1) * 64, wn = (w & 1) * 32;

    const int srow = w * 16 + (lane >> 2);
    const int scol = (lane & 3) * 8;
    const u16* pA0 = A + (size_t)(m0 + srow) * K + scol;
    const u16* pA1 = pA0 + (size_t)64 * K;
    const u16* pB1 = B1t + (size_t)(n0 + srow) * K + scol;
    const u16* pB2 = B2t + (size_t)(n0 + srow) * K + scol;

    f32x4 acc1[4][2], acc2[4][2];
    #pragma unroll
    for (int i = 0; i < 4; ++i)
        #pragma unroll
        for (int j = 0; j < 2; ++j) {
            acc1[i][j] = (f32x4){0.f, 0.f, 0.f, 0.f};
            acc2[i][j] = (f32x4){0.f, 0.f, 0.f, 0.f};
        }

    for (int kb = 0; kb < K; kb += 64) {
        __syncthreads();
        stage16(pA0 + kb,      (char*)As[0] + w * 1024);
        stage16(pA1 + kb,      (char*)As[0] + 4096 + w * 1024);
        stage16(pB1 + kb,      (char*)B1s[0] + w * 1024);
        stage16(pB2 + kb,      (char*)B2s[0] + w * 1024);
        stage16(pA0 + kb + 32, (char*)As[1] + w * 1024);
        stage16(pA1 + kb + 32, (char*)As[1] + 4096 + w * 1024);
        stage16(pB1 + kb + 32, (char*)B1s[1] + w * 1024);
        stage16(pB2 + kb + 32, (char*)B2s[1] + w * 1024);
        __syncthreads();
        #pragma unroll
        for (int hf = 0; hf < 2; ++hf) {
            bf16x8 af[4], b1r[2], b2r[2];
            #pragma unroll
            for (int mi = 0; mi < 4; ++mi)
                af[mi] = *(const bf16x8*)((char*)As[hf] + (wm + mi * 16 + t) * 64 + quad * 16);
            #pragma unroll
            for (int ni = 0; ni < 2; ++ni) {
                b1r[ni] = *(const bf16x8*)((char*)B1s[hf] + (wn + ni * 16 + t) * 64 + quad * 16);
                b2r[ni] = *(const bf16x8*)((char*)B2s[hf] + (wn + ni * 16 + t) * 64 + quad * 16);
            }
            #pragma unroll
            for (int mi = 0; mi < 4; ++mi)
                #pragma unroll
                for (int ni = 0; ni < 2; ++ni) {
                    acc1[mi][ni] = __builtin_amdgcn_mfma_f32_16x16x32_bf16(af[mi], b1r[ni],
                                                                          acc1[mi][ni], 0, 0, 0);
                    acc2[mi][ni] = __builtin_amdgcn_mfma_f32_16x16x32_bf16(af[mi], b2r[ni],
                                                                          acc2[mi][ni], 0, 0, 0);
                }
        }
    }
    #pragma unroll
    for (int mi = 0; mi < 4; ++mi) {
        const int row0 = m0 + wm + mi * 16 + quad * 4;
        #pragma unroll
        for (int ni = 0; ni < 2; ++ni) {
            const int col = n0 + wn + ni * 16 + t;
            float mv[4];
            #pragma unroll
            for (int r = 0; r < 4; ++r) {
                const float a = acc1[mi][ni][r];
                mv[r] = (a / (1.f + __expf(-a))) * acc2[mi][ni][r];
            }
            #pragma unroll
            for (int r = 0; r < 4; r += 2) {
                const uint32_t pk2 = cvt_pk_bf16(mv[r], mv[r + 1]);
                Cout[(size_t)(row0 + r) * N + col]     = (u16)pk2;
                Cout[(size_t)(row0 + r + 1) * N + col] = (u16)(pk2 >> 16);
            }
        }
    }
}

// ---- flash attention: qkv (4096 x 3072 bf16, roped), y (4096 x 1024 bf16) ----
// R13 structure + SINGLE-BARRIER DOUBLE-BUFFER (T14 issue-early/write-late):
// grid = 512 blocks = 2/CU (grid-limited), so 46 KB LDS is occupancy-free now
// (R1's dbuf failed at 1024 blocks where it cut 4/CU -> 3/CU). Per iteration:
// issue next-tile loads, compute from buf[cur], write regs to buf[cur^1], ONE
// barrier. KVBLK=64 (R12's 128 spilled). Pair-balanced; XCD-grouped; DPP softmax.
__global__ __launch_bounds__(256) void attn_kernel(const u16* __restrict__ qkv,
                                                   const int* __restrict__ ymask,
                                                   u16* __restrict__ y) {
    const int gid = blockIdx.x;              // 0..511
    const int xcd = gid & 7;
    const int j2 = gid >> 3;                 // 0..63
    const int slot = j2 >> 4;                // 0..3
    const int pairk = j2 & 15;               // 0..15
    const int group = slot * 8 + xcd;        // 0..31
    const int h = group & 15, b = group >> 4;
    const int tid = threadIdx.x;
    const int w = tid >> 6, lane = tid & 63;
    const int quad = lane >> 4, t = lane & 15;

    __shared__ __attribute__((aligned(16))) u16 Ks[2][64 * 72];   // [key][d], 144B rows
    __shared__ __attribute__((aligned(16))) u16 Vts[2][64 * 72];  // [d][key], swizzled
    __shared__ __attribute__((aligned(16))) u16 Ps[4][16 * 72];   // per-wave P [m][key]
    __shared__ int ymL[64];
    if (pairk == 0 && tid < 64) ymL[tid] = ymask[b * 64 + tid];

    // staging assignment: thread -> (key = tid>>3 and +32, dg = tid&7)
    const int skey = tid >> 3, sdg = tid & 7;
    const u16* pK = qkv + (size_t)(b * 2048 + skey) * 3072 + h * 64 + sdg * 8 + 1024;
    const int sblk0 = (skey >> 3) ^ sdg;          // Vts block for keys 0..31 set
    const int sblk1 = (4 + (skey >> 3)) ^ sdg;    // keys 32..63 set

    for (int seg = 0; seg < 2; ++seg) {
        const int qt = seg ? pairk : 31 - pairk;  // long segment first
        const int q0 = qt * 64;

        bf16x8 aQ[2];
        {
            const u16* qp = qkv + (size_t)(b * 2048 + q0 + w * 16 + t) * 3072 + h * 64 + quad * 8;
            aQ[0] = *(const bf16x8*)qp;
            aQ[1] = *(const bf16x8*)(qp + 32);
            #pragma unroll
            for (int i = 0; i < 8; ++i) {   // fold 1/sqrt(64): *2^-3 exact in bf16
                aQ[0][i] = (short)f2b(b2f((u16)aQ[0][i]) * 0.125f);
                aQ[1][i] = (short)f2b(b2f((u16)aQ[1][i]) * 0.125f);
            }
        }

        // ---- prologue: stage tile 0 into buffer 0 ----
        {
            const uint4 kv0 = *(const uint4*)pK;
            const uint4 vv0 = *(const uint4*)(pK + 1024);
            const uint4 kv1 = *(const uint4*)(pK + 98304);   // +32*3072
            const uint4 vv1 = *(const uint4*)(pK + 99328);
            __syncthreads();             // previous segment's LDS reads complete
            *(uint4*)((char*)Ks[0] + skey * 144 + sdg * 16) = kv0;
            *(uint4*)((char*)Ks[0] + (skey + 32) * 144 + sdg * 16) = kv1;
            const u16* vp0 = (const u16*)&vv0;
            const u16* vp1 = (const u16*)&vv1;
            #pragma unroll
            for (int jj = 0; jj < 8; ++jj) {
                const int row = sdg * 8 + jj;
                Vts[0][row * 72 + sblk0 * 8 + (skey & 7)] = vp0[jj];
                Vts[0][row * 72 + sblk1 * 8 + (skey & 7)] = vp1[jj];
            }
        }
        __syncthreads();

        f32x4 accO[4] = {(f32x4){0,0,0,0},(f32x4){0,0,0,0},(f32x4){0,0,0,0},(f32x4){0,0,0,0}};
        float mOld[4] = {-INFINITY, -INFINITY, -INFINITY, -INFINITY};
        float lSum[4] = {0.f, 0.f, 0.f, 0.f};

        int cur = 0;
        for (int kb = 0; kb <= qt; ++kb) {
            const bool more = (kb < qt);
            // next tile's global loads issued NOW; latency hides under compute
            uint4 nk0, nv0, nk1, nv1;
            if (more) {
                const u16* pk = pK + (size_t)(kb + 1) * 196608;   // (kb+1)*64*3072
                nk0 = *(const uint4*)pk;
                nv0 = *(const uint4*)(pk + 1024);
                nk1 = *(const uint4*)(pk + 98304);
                nv1 = *(const uint4*)(pk + 99328);
            }
            const u16* KsC  = Ks[cur];
            const u16* VtsC = Vts[cur];

            float s[4][4];
            __builtin_amdgcn_s_setprio(1);
            #pragma unroll
            for (int ni = 0; ni < 4; ++ni) {
                bf16x8 bK0 = *(const bf16x8*)((const char*)KsC + (ni * 16 + t) * 144 + quad * 16);
                bf16x8 bK1 = *(const bf16x8*)((const char*)KsC + (ni * 16 + t) * 144 + 64 + quad * 16);
                f32x4 sa = (f32x4){0.f, 0.f, 0.f, 0.f};
                sa = __builtin_amdgcn_mfma_f32_16x16x32_bf16(aQ[0], bK0, sa, 0, 0, 0);
                sa = __builtin_amdgcn_mfma_f32_16x16x32_bf16(aQ[1], bK1, sa, 0, 0, 0);
                #pragma unroll
                for (int r = 0; r < 4; ++r) s[ni][r] = sa[r];
            }
            __builtin_amdgcn_s_setprio(0);

            // mask only on the diagonal tile; ym text-mask only in the qt==0 tile.
            if (kb == qt) {
                const int irow = q0 + w * 16 + quad * 4;
                #pragma unroll
                for (int ni = 0; ni < 4; ++ni)
                    #pragma unroll
                    for (int r = 0; r < 4; ++r) {
                        const int i = irow + r, j = kb * 64 + ni * 16 + t;
                        const bool ok = (j <= i) || (qt == 0 && ymL[i & 63] && ymL[j & 63]);
                        if (!ok) s[ni][r] = -INFINITY;
                    }
            }

            float alpha[4];
            bool upd = false;
            #pragma unroll
            for (int r = 0; r < 4; ++r) {
                float mt = fmaxf(fmaxf(s[0][r], s[1][r]), fmaxf(s[2][r], s[3][r]));
                mt = rowmax16(mt);                       // DPP, VALU-rate
                const float mNew = fmaxf(mOld[r], mt);
                upd = upd || (mNew > mOld[r]);
                alpha[r] = __expf(mOld[r] - mNew);
                #pragma unroll
                for (int ni = 0; ni < 4; ++ni) s[ni][r] = __expf(s[ni][r] - mNew);
                mOld[r] = mNew;
            }

            // P (C-layout) -> per-wave LDS, issued early; ds_write latency hides
            // under the DPP sum-reduces below. Same-wave, no barrier needed.
            u16* Pw = Ps[w];
            #pragma unroll
            for (int ni = 0; ni < 4; ++ni)
                #pragma unroll
                for (int r = 0; r < 4; ++r)
                    Pw[(quad * 4 + r) * 72 + ni * 16 + t] = f2b(s[ni][r]);

            #pragma unroll
            for (int r = 0; r < 4; ++r) {
                float rs = (s[0][r] + s[1][r]) + (s[2][r] + s[3][r]);
                rs = rowsum16(rs);                       // DPP, VALU-rate
                lSum[r] = lSum[r] * alpha[r] + rs;
            }
            if (__any(upd)) {               // skip O-rescale when no row's max moved
                #pragma unroll
                for (int dt = 0; dt < 4; ++dt)
                    #pragma unroll
                    for (int r = 0; r < 4; ++r) accO[dt][r] *= alpha[r];
            }

            bf16x8 aP0 = *(const bf16x8*)((char*)Pw + t * 144 + quad * 16);
            bf16x8 aP1 = *(const bf16x8*)((char*)Pw + t * 144 + 64 + quad * 16);
            __builtin_amdgcn_s_setprio(1);
            #pragma unroll
            for (int dt = 0; dt < 4; ++dt) {
                const int row = dt * 16 + t, rb = row >> 3;
                bf16x8 bV0 = *(const bf16x8*)((const char*)VtsC + row * 144 + ((quad ^ rb) << 4));
                bf16x8 bV1 = *(const bf16x8*)((const char*)VtsC + row * 144 + (((4 + quad) ^ rb) << 4));
                accO[dt] = __builtin_amdgcn_mfma_f32_16x16x32_bf16(aP0, bV0, accO[dt], 0, 0, 0);
                accO[dt] = __builtin_amdgcn_mfma_f32_16x16x32_bf16(aP1, bV1, accO[dt], 0, 0, 0);
            }
            __builtin_amdgcn_s_setprio(0);

            if (!more) break;
            // write next tile into the OTHER buffer: nobody reads it this iteration,
            // so a single end-of-iteration barrier suffices.
            {
                u16* KsN  = Ks[cur ^ 1];
                u16* VtsN = Vts[cur ^ 1];
                *(uint4*)((char*)KsN + skey * 144 + sdg * 16) = nk0;
                *(uint4*)((char*)KsN + (skey + 32) * 144 + sdg * 16) = nk1;
                const u16* vp0 = (const u16*)&nv0;
                const u16* vp1 = (const u16*)&nv1;
                #pragma unroll
                for (int jj = 0; jj < 8; ++jj) {
                    const int row = sdg * 8 + jj;
                    VtsN[row * 72 + sblk0 * 8 + (skey & 7)] = vp0[jj];
                    VtsN[row * 72 + sblk1 * 8 + (skey & 7)] = vp1[jj];
                }
            }
            __syncthreads();                 // single barrier per K-tile
            cur ^= 1;
        }
        const int orow = q0 + w * 16 + quad * 4;
        #pragma unroll
        for (int dt = 0; dt < 4; ++dt)
            #pragma unroll
            for (int r = 0; r < 4; ++r) {
                const size_t idx = (size_t)(b * 2048 + orow + r) * 1024 + h * 64 + dt * 16 + t;
                y[idx] = f2b(accO[dt][r] / lSum[r]);
            }
    }
}

extern "C" void kernel_launch(void* const* d_in, const int* in_sizes, int n_in,
                              void* d_out, int out_size, void* d_ws, size_t ws_size,
                              hipStream_t stream) {
    const float* x     = (const float*)d_in[0];
    const int*   ym    = (const int*)d_in[1];
    const float* Wqkv  = (const float*)d_in[2];
    const float* Wattn = (const float*)d_in[3];
    const float* s1    = (const float*)d_in[4];
    const float* s2    = (const float*)d_in[5];
    const float* Wfc1  = (const float*)d_in[6];
    const float* Wfc2  = (const float*)d_in[7];
    const float* Wmlp  = (const float*)d_in[8];

    char* ws = (char*)d_ws;
    u16*    h    = (u16*)(ws + 0);          // 8 MB bf16; reused as attention output
    u16*    qkv  = (u16*)(ws + 8388608);    // 24 MB bf16; later reused as fc1/m
    u16*    fc1  = qkv;
    float*  xr   = (float*)(ws + 33554432); // 16 MB fp32 residual
    u16*    WtA  = (u16*)(ws + 50331648);   // 2 MB
    u16*    WtF1 = (u16*)(ws + 52428800);   // 5.5 MB
    u16*    WtF2 = (u16*)(ws + 58195968);   // 5.5 MB
    u16*    WtM  = (u16*)(ws + 63963136);   // 5.5 MB
    u16*    WtQ  = (u16*)(ws + 73400320);   // 6 MB
    const dim3 tb(32, 8);

    prep_kernel<<<16640, tb, 0, stream>>>(Wqkv, Wattn, Wfc1, Wfc2, Wmlp,
                                          WtQ, WtA, WtF1, WtF2, WtM, x, s1, h);
    gemm_bt<0><<<dim3(24, 32), 256, 0, stream>>>(h, WtQ, qkv, nullptr, 3072, 1024);
    rope_kernel<<<512, 256, 0, stream>>>(qkv);
    attn_kernel<<<512, 256, 0, stream>>>(qkv, ym, h);   // h dead -> y
    gemm_bt64<1><<<dim3(16, 32), 256, 0, stream>>>(h, WtA, xr, x, 1024, 1024);
    rmsnorm_f32<<<4096, 256, 0, stream>>>(xr, s2, h);
    gemm_fc<<<dim3(44, 32), 256, 0, stream>>>(h, WtF1, WtF2, fc1, 2816, 1024);
    gemm_bt64<1><<<dim3(16, 32), 256, 0, stream>>>(fc1, WtM, (float*)d_out, xr, 1024, 2816);
}